// Round 4
// baseline (5787.732 us; speedup 1.0000x reference)
//
#include <hip/hip_runtime.h>

typedef short bf16x8 __attribute__((ext_vector_type(8)));
typedef float f32x4 __attribute__((ext_vector_type(4)));

__device__ __forceinline__ float bf2f(unsigned short u) {
    union { unsigned int i; float f; } c; c.i = ((unsigned int)u) << 16; return c.f;
}
__device__ __forceinline__ unsigned short f2bf(float f) {
    union { float f; unsigned int i; } c; c.f = f;
    unsigned int u = c.i;
    u += 0x7fffu + ((u >> 16) & 1u);          // round-to-nearest-even
    return (unsigned short)(u >> 16);
}

// async global->LDS, 16B per lane; mapping must be wave-uniform base + lane*16
__device__ __forceinline__ void gload_lds16(const unsigned short* g, unsigned short* l) {
    __builtin_amdgcn_global_load_lds(
        (const __attribute__((address_space(1))) void*)g,
        (__attribute__((address_space(3))) void*)l, 16, 0, 0);
}

// ---------------------------------------------------------------------------
// fpn fp32 NCHW [4][256][160][160] -> bf16 NHWC padded [4][162][162][256]
__global__ void transpose_pad(const float* __restrict__ x, unsigned short* __restrict__ xpad) {
    int idx = blockIdx.x * 256 + threadIdx.x;       // 3,276,800 exact
    int w = idx % 160; int t = idx / 160;
    int cv = t % 32;   t /= 32;
    int h = t % 160;   int n = t / 160;
    const float* src = x + (((size_t)(n * 256 + cv * 8) * 160 + h) * 160 + w);
    unsigned short us[8];
#pragma unroll
    for (int k = 0; k < 8; ++k) us[k] = f2bf(src[(size_t)k * 25600]);
    uint4 o;
    o.x = (unsigned int)us[0] | ((unsigned int)us[1] << 16);
    o.y = (unsigned int)us[2] | ((unsigned int)us[3] << 16);
    o.z = (unsigned int)us[4] | ((unsigned int)us[5] << 16);
    o.w = (unsigned int)us[6] | ((unsigned int)us[7] << 16);
    *(uint4*)(xpad + ((size_t)((n * 162 + h + 1) * 162) + (w + 1)) * 256 + cv * 8) = o;
}

// zero the 1-wide border of one padded NHWC buffer
__device__ __forceinline__ void zero_border_one(unsigned short* buf, int C, int idx) {
    int CV = C >> 3;
    int cv = idx % CV; int t = idx / CV;
    int p = t % 644;   int n = t / 644;
    int h, w;
    if (p < 162)      { h = 0;   w = p; }
    else if (p < 324) { h = 161; w = p - 162; }
    else { int q = p - 324; h = 1 + (q >> 1); w = (q & 1) ? 161 : 0; }
    uint4 z = make_uint4(0u, 0u, 0u, 0u);
    *(uint4*)(buf + ((size_t)((n * 162 + h) * 162) + w) * C + cv * 8) = z;
}

// border-zero xpad + nbr buf1's (C=256) + nbr buf2's (C=128), one dispatch
__global__ void zero_all(unsigned short* __restrict__ xpad,
                         unsigned short* __restrict__ buf1, size_t s1,
                         unsigned short* __restrict__ buf2, size_t s2, int nbr) {
    int idx = blockIdx.x * 256 + threadIdx.x;
    if (idx < 82432) { zero_border_one(xpad, 256, idx); return; }
    idx -= 82432;
    int nb1 = nbr * 82432;
    if (idx < nb1) { zero_border_one(buf1 + (size_t)(idx / 82432) * s1, 256, idx % 82432); return; }
    idx -= nb1;
    int nb2 = nbr * 41216;
    if (idx < nb2) { zero_border_one(buf2 + (size_t)(idx / 41216) * s2, 128, idx % 41216); }
}

// ---------------------------------------------------------------------------
// Weight pack: fp32 OIHW [CO][256][3][3] -> per-128-co-tile fragment-order:
//   tile = 294912 shorts (576KB).
//   tp in 0..3 (taps {2tp,2tp+1}): block tp*65536; within: q(0..7)*8192;
//     idx = (g*128+co)*8+e, g 0..7: tap=2tp+(g>>2), ci=q*32+(g&3)*8+e
//   tp=4 (tap 8): block 262144, q*4096; idx=(g*128+co)*8+e, g 0..3: ci=q*32+g*8+e
// Tiles 0..5: layer1 (br=t>>1, coBase=(t&1)*128) -> w1p; 6..8: layer2 -> w2p.
__global__ void pack_all(const float* __restrict__ s0, const float* __restrict__ s1,
                         const float* __restrict__ s2, const float* __restrict__ s3,
                         const float* __restrict__ s4, const float* __restrict__ s5,
                         unsigned short* __restrict__ w1p, unsigned short* __restrict__ w2p) {
    int idx = blockIdx.x * 256 + threadIdx.x;   // 9*294912 = 2,654,208 exact
    int t = idx / 294912, r = idx - t * 294912;
    const float* src; unsigned short* dst; int coBase;
    if (t < 6) {
        int br = t >> 1;
        src = (br == 0) ? s0 : (br == 1) ? s1 : s2;
        coBase = (t & 1) * 128;
        dst = w1p + (size_t)t * 294912;
    } else {
        int br = t - 6;
        src = (br == 0) ? s3 : (br == 1) ? s4 : s5;
        coBase = 0;
        dst = w2p + (size_t)br * 294912;
    }
    int tap, ci, o;
    if (r < 262144) {
        int tp = r >> 16, rem = r & 65535;
        int q = rem >> 13, r2 = rem & 8191;
        int e = r2 & 7, gco = r2 >> 3;
        int co = gco & 127, g = gco >> 7;
        tap = tp * 2 + (g >> 2);
        ci = q * 32 + (g & 3) * 8 + e;
        o = coBase + co;
    } else {
        int rem = r - 262144;
        int q = rem >> 12, r2 = rem & 4095;
        int e = r2 & 7, gco = r2 >> 3;
        int co = gco & 127, g = gco >> 7;
        tap = 8;
        ci = q * 32 + g * 8 + e;
        o = coBase + co;
    }
    dst[r] = f2bf(src[((size_t)(o * 256 + ci)) * 9 + tap]);
}

// ---------------------------------------------------------------------------
// 3x3 conv, implicit GEMM, bf16 MFMA 16x16x32.
// R4: R2's proven sync structure (sync; stage; sync; compute) with LDS cut
// to 37.25KB so 4 blocks/CU are resident (16 waves/CU): one block's DMA
// drain overlaps three others' compute.
//  - A window = ONE tap-pair chunk (16KB), 5 windows/q: {t01}{t23}{t45}{t67}{t8}
//  - B layout tightened [g4][340][8] = 21.25KB (exact strip, no padding);
//    staged in 5 full rounds + 1 exec-masked partial round (tid<80).
//  - wave tile 64co x 128sp (acc 128 VGPR), block 128co x 256sp.
template<int COT, int BPB>
__global__ __launch_bounds__(256, 4) void conv3x3_mfma(
        const unsigned short* __restrict__ xpad0, size_t xstride,
        const unsigned short* __restrict__ wpk0, size_t wstride,
        unsigned short* __restrict__ ypad0, size_t ystride,
        float* __restrict__ stats, int sstride) {
    __shared__ __align__(16) unsigned short As[8192];    // 16KB: [g8][co128][e8] one tap-pair
    __shared__ __align__(16) unsigned short Bs[10880];   // 21.25KB: [g4][pos340][e8]

    const int br = blockIdx.x / BPB;
    int bid = blockIdx.x % BPB;
    const unsigned short* xpad = xpad0 + (size_t)br * xstride;
    const unsigned short* wpk  = wpk0 + (size_t)br * wstride;
    unsigned short* ypad       = ypad0 + (size_t)br * ystride;
    float* sum   = stats + (size_t)br * sstride;
    float* sumsq = sum + 256;

    const int tid = threadIdx.x;
    const int wv = tid >> 6, lane = tid & 63;
    const int quad = lane >> 4, l15 = lane & 15;
    const int wco = wv >> 1, wsp = wv & 1;

    const int wt = bid % 5;
    const int ht = (bid / 5) % 20;
    const int n = (bid / 100) % 4;
    const int tile = bid / 400;            // 0..1 for COT=256, 0 for COT=128
    const int co0 = tile * 128;
    const int h0 = ht * 8, w0 = wt * 32;   // halo origin in padded coords

    const unsigned short* wtile = wpk + (size_t)tile * 294912;

    // B staging source offsets: 1360 lane-slots (5 full rounds + 80 threads)
    // strip: 10 rows x 34 cols, layout Bs[g4][pos340][e8], pos = row*34+col
    int boff[6];
#pragma unroll
    for (int r = 0; r < 6; ++r) {
        int slot = r * 256 + tid;          // 0..1535; only <1360 used
        if (slot > 1359) slot = 1359;
        int g = slot / 340, p = slot - g * 340;
        int prow = p / 34, pcol = p - prow * 34;
        boff[r] = ((n * 162 + h0 + prow) * 162 + (w0 + pcol)) * 256 + g * 8;
    }

    // b-frag base positions for this wave's 8 spatial frags
    int p0[8];
#pragma unroll
    for (int j = 0; j < 8; ++j) {
        int sp = wsp * 128 + j * 16 + l15;
        p0[j] = (sp >> 5) * 34 + (sp & 31);
    }

    f32x4 acc[4][8];
#pragma unroll
    for (int i = 0; i < 4; ++i)
#pragma unroll
        for (int j = 0; j < 8; ++j) acc[i][j] = (f32x4){0.f, 0.f, 0.f, 0.f};

    for (int q = 0; q < 8; ++q) {          // ci chunk of 32
#pragma unroll
        for (int w = 0; w < 5; ++w) {      // windows: {t01}{t23}{t45}{t67}{t8}
            __syncthreads();               // prior window's LDS reads complete
            if (w == 0) {                  // B strip for this q
                const unsigned short* bqp = xpad + q * 32;
#pragma unroll
                for (int r = 0; r < 5; ++r)
                    gload_lds16(bqp + boff[r], (unsigned short*)Bs + (r * 256 + tid) * 8);
                if (tid < 80)
                    gload_lds16(bqp + boff[5], (unsigned short*)Bs + (1280 + tid) * 8);
            }
            if (w < 4) {                   // one 16KB tap-pair chunk
                const unsigned short* asrc = wtile + w * 65536 + q * 8192 + tid * 8;
#pragma unroll
                for (int c = 0; c < 4; ++c)
                    gload_lds16(asrc + c * 2048, (unsigned short*)As + c * 2048 + tid * 8);
            } else {                       // tap 8: 8KB
                const unsigned short* asrc = wtile + 262144 + q * 4096 + tid * 8;
#pragma unroll
                for (int c = 0; c < 2; ++c)
                    gload_lds16(asrc + c * 2048, (unsigned short*)As + c * 2048 + tid * 8);
            }
            __syncthreads();               // drain DMA: tiles ready

#pragma unroll
            for (int ts = 0; ts < 2; ++ts) {
                if (w == 4 && ts == 1) continue;      // folds at compile time
                const int TAP = (w < 4) ? (w * 2 + ts) : 8;
                const int dh = TAP / 3, dw = TAP % 3;
                const int toff = dh * 34 + dw;
                const int g0 = (w < 4 ? ts * 4 : 0) + quad;
                bf16x8 a[4];
#pragma unroll
                for (int i = 0; i < 4; ++i)
                    a[i] = *(const bf16x8*)(As + (size_t)(g0 * 128 + wco * 64 + i * 16 + l15) * 8);
#pragma unroll
                for (int jh = 0; jh < 2; ++jh) {      // two b-quartets: caps live regs
                    bf16x8 b[4];
#pragma unroll
                    for (int j = 0; j < 4; ++j)
                        b[j] = *(const bf16x8*)(Bs + (size_t)(quad * 340 + p0[jh * 4 + j] + toff) * 8);
#pragma unroll
                    for (int i = 0; i < 4; ++i)
#pragma unroll
                        for (int j = 0; j < 4; ++j)
                            acc[i][jh * 4 + j] = __builtin_amdgcn_mfma_f32_16x16x32_bf16(
                                a[i], b[j], acc[i][jh * 4 + j], 0, 0, 0);
                }
            }
        }
    }

    // epilogue: store y (bf16, NHWC padded interior) + BN partial stats
#pragma unroll
    for (int i = 0; i < 4; ++i) {
        const int co_e = wco * 64 + i * 16 + quad * 4;
#pragma unroll
        for (int j = 0; j < 8; ++j) {
            const int sp = wsp * 128 + j * 16 + l15;
            const int jh = sp >> 5, jw = sp & 31;
            f32x4 v = acc[i][j];
            ushort4 pk;
            pk.x = f2bf(v[0]); pk.y = f2bf(v[1]); pk.z = f2bf(v[2]); pk.w = f2bf(v[3]);
            *(ushort4*)(ypad + ((size_t)((n * 162 + h0 + jh + 1) * 162) + (w0 + jw + 1)) * COT
                        + co0 + co_e) = pk;
        }
#pragma unroll
        for (int r = 0; r < 4; ++r) {
            float s1 = 0.f, s2 = 0.f;
#pragma unroll
            for (int j = 0; j < 8; ++j) { float v = acc[i][j][r]; s1 += v; s2 += v * v; }
#pragma unroll
            for (int m = 1; m < 16; m <<= 1) {
                s1 += __shfl_xor(s1, m, 64);
                s2 += __shfl_xor(s2, m, 64);
            }
            if (l15 == 0) {
                atomicAdd(&sum[co0 + co_e + r], s1);
                atomicAdd(&sumsq[co0 + co_e + r], s2);
            }
        }
    }
}

// ---------------------------------------------------------------------------
// fused BN finalize + in-place relu(y*scale+shift); branch-fused via BPB
template<int C, int BPB>
__global__ void bn_apply(unsigned short* __restrict__ buf0, size_t bstride,
                         const float* __restrict__ stats, int sstride,
                         const float* g0, const float* g1, const float* g2,
                         const float* be0, const float* be1, const float* be2) {
    const int br = blockIdx.x / BPB;
    unsigned short* buf = buf0 + (size_t)br * bstride;
    const float* sum = stats + (size_t)br * sstride;
    const float* sumsq = sum + 256;
    const float* gamma = (br == 0) ? g0 : (br == 1) ? g1 : g2;
    const float* beta  = (br == 0) ? be0 : (br == 1) ? be1 : be2;

    __shared__ float s_sc[C], s_sh[C];
    if (threadIdx.x < C) {
        int c = threadIdx.x;
        const float inv = 1.0f / 102400.0f;
        float m = sum[c] * inv;
        float v = sumsq[c] * inv - m * m;
        float sc = gamma[c] * rsqrtf(v + 1e-5f);
        s_sc[c] = sc;
        s_sh[c] = beta[c] - m * sc;
    }
    __syncthreads();

    constexpr int CV = C / 8;
    int idx = (blockIdx.x % BPB) * 256 + threadIdx.x;   // 4*25600*CV exact per branch
    int cv = idx % CV; int pos = idx / CV;
    int w = pos % 160; int h = (pos / 160) % 160; int n = pos / 25600;
    unsigned short* p = buf + ((size_t)((n * 162 + h + 1) * 162) + (w + 1)) * C + cv * 8;
    uint4 v = *(const uint4*)p;
    unsigned int ua[4] = {v.x, v.y, v.z, v.w};
    unsigned int ob[4];
#pragma unroll
    for (int j = 0; j < 4; ++j) {
        int c = cv * 8 + j * 2;
        float f0 = bf2f((unsigned short)(ua[j] & 0xffffu)) * s_sc[c] + s_sh[c];
        float f1 = bf2f((unsigned short)(ua[j] >> 16)) * s_sc[c + 1] + s_sh[c + 1];
        f0 = fmaxf(f0, 0.f); f1 = fmaxf(f1, 0.f);
        ob[j] = (unsigned int)f2bf(f0) | ((unsigned int)f2bf(f1) << 16);
    }
    uint4 o = make_uint4(ob[0], ob[1], ob[2], ob[3]);
    *(uint4*)p = o;
}

// ---------------------------------------------------------------------------
// head conv: z [4][162][162][128] bf16 padded -> out [4][CO][160][160] fp32 (+bias)
template<int CO>
__global__ __launch_bounds__(256) void head_conv(const unsigned short* __restrict__ z,
                                                 const float* __restrict__ w,
                                                 const float* __restrict__ bias,
                                                 float* __restrict__ out) {
    __shared__ float s_w[CO * 9 * 128];
    for (int t = threadIdx.x; t < CO * 9 * 128; t += 256) {
        int ci = t % 128; int r = t / 128;
        int tap = r % 9;  int o = r / 9;
        s_w[t] = w[((size_t)(o * 128 + ci)) * 9 + tap];
    }
    __syncthreads();

    const int pos = blockIdx.x * 256 + threadIdx.x;   // 102400 exact
    const int pw = pos % 160, ph = (pos / 160) % 160, pn = pos / 25600;
    float acc[CO];
#pragma unroll
    for (int o = 0; o < CO; ++o) acc[o] = bias[o];

#pragma unroll
    for (int dh = 0; dh < 3; ++dh)
#pragma unroll
        for (int dw = 0; dw < 3; ++dw) {
            const int tap = dh * 3 + dw;
            const unsigned short* zp = z + ((size_t)((pn * 162 + ph + dh) * 162) + (pw + dw)) * 128;
            for (int c8 = 0; c8 < 16; ++c8) {
                uint4 v = *(const uint4*)(zp + c8 * 8);
                unsigned int ua[4] = {v.x, v.y, v.z, v.w};
                float xv[8];
#pragma unroll
                for (int j = 0; j < 4; ++j) {
                    xv[2 * j]     = bf2f((unsigned short)(ua[j] & 0xffffu));
                    xv[2 * j + 1] = bf2f((unsigned short)(ua[j] >> 16));
                }
#pragma unroll
                for (int o = 0; o < CO; ++o) {
                    const float* wp = &s_w[(o * 9 + tap) * 128 + c8 * 8];
                    float4 w0 = *(const float4*)wp;
                    float4 w1 = *(const float4*)(wp + 4);
                    acc[o] = fmaf(xv[0], w0.x, acc[o]);
                    acc[o] = fmaf(xv[1], w0.y, acc[o]);
                    acc[o] = fmaf(xv[2], w0.z, acc[o]);
                    acc[o] = fmaf(xv[3], w0.w, acc[o]);
                    acc[o] = fmaf(xv[4], w1.x, acc[o]);
                    acc[o] = fmaf(xv[5], w1.y, acc[o]);
                    acc[o] = fmaf(xv[6], w1.z, acc[o]);
                    acc[o] = fmaf(xv[7], w1.w, acc[o]);
                }
            }
        }
#pragma unroll
    for (int o = 0; o < CO; ++o)
        out[((size_t)(pn * CO + o)) * 25600 + ph * 160 + pw] = acc[o];
}

// two CO=1 heads fused (shrink + centroid)
__global__ __launch_bounds__(256) void head_conv_dual(const unsigned short* __restrict__ z,
                                                      const float* __restrict__ w1, const float* __restrict__ b1,
                                                      const float* __restrict__ w2, const float* __restrict__ b2,
                                                      float* __restrict__ out1, float* __restrict__ out2) {
    __shared__ float s_w[2 * 9 * 128];
    for (int t = threadIdx.x; t < 2 * 9 * 128; t += 256) {
        int ci = t % 128; int r = t / 128;
        int tap = r % 9;  int which = r / 9;
        const float* src = which ? w2 : w1;
        s_w[t] = src[(size_t)ci * 9 + tap];
    }
    __syncthreads();

    const int pos = blockIdx.x * 256 + threadIdx.x;
    const int pw = pos % 160, ph = (pos / 160) % 160, pn = pos / 25600;
    float a1 = b1[0], a2 = b2[0];

#pragma unroll
    for (int dh = 0; dh < 3; ++dh)
#pragma unroll
        for (int dw = 0; dw < 3; ++dw) {
            const int tap = dh * 3 + dw;
            const unsigned short* zp = z + ((size_t)((pn * 162 + ph + dh) * 162) + (pw + dw)) * 128;
            for (int c8 = 0; c8 < 16; ++c8) {
                uint4 v = *(const uint4*)(zp + c8 * 8);
                unsigned int ua[4] = {v.x, v.y, v.z, v.w};
                float xv[8];
#pragma unroll
                for (int j = 0; j < 4; ++j) {
                    xv[2 * j]     = bf2f((unsigned short)(ua[j] & 0xffffu));
                    xv[2 * j + 1] = bf2f((unsigned short)(ua[j] >> 16));
                }
                const float* wp1 = &s_w[tap * 128 + c8 * 8];
                const float* wp2 = &s_w[1152 + tap * 128 + c8 * 8];
#pragma unroll
                for (int e = 0; e < 8; ++e) {
                    a1 = fmaf(xv[e], wp1[e], a1);
                    a2 = fmaf(xv[e], wp2[e], a2);
                }
            }
        }
    out1[(size_t)pn * 25600 + ph * 160 + pw] = a1;
    out2[(size_t)pn * 25600 + ph * 160 + pw] = a2;
}

// ---------------------------------------------------------------------------
extern "C" void kernel_launch(void* const* d_in, const int* in_sizes, int n_in,
                              void* d_out, int out_size, void* d_ws, size_t ws_size,
                              hipStream_t stream) {
    const float* fpn = (const float*)d_in[0];
    const float* W1[3] = {(const float*)d_in[1],  (const float*)d_in[11], (const float*)d_in[19]};
    const float* G1[3] = {(const float*)d_in[2],  (const float*)d_in[12], (const float*)d_in[20]};
    const float* B1[3] = {(const float*)d_in[3],  (const float*)d_in[13], (const float*)d_in[21]};
    const float* W2[3] = {(const float*)d_in[4],  (const float*)d_in[14], (const float*)d_in[22]};
    const float* G2[3] = {(const float*)d_in[5],  (const float*)d_in[15], (const float*)d_in[23]};
    const float* B2[3] = {(const float*)d_in[6],  (const float*)d_in[16], (const float*)d_in[24]};
    const float* w_shrink = (const float*)d_in[7];  const float* b_shrink = (const float*)d_in[8];
    const float* w_cent   = (const float*)d_in[9];  const float* b_cent   = (const float*)d_in[10];
    const float* w_p3     = (const float*)d_in[17]; const float* b_p3     = (const float*)d_in[18];
    const float* w_s3     = (const float*)d_in[25]; const float* b_s3     = (const float*)d_in[26];
    float* out = (float*)d_out;

    const size_t S1 = (size_t)4 * 162 * 162 * 256;   // shorts per buf1
    const size_t S2 = (size_t)4 * 162 * 162 * 128;   // shorts per buf2
    const size_t need_fused = S1 * 2 * 4 /*xpad+3*buf1*/ + S2 * 2 * 3
                              + (size_t)9 * 294912 * 2 + 6 * 512 * 4;

    char* ws = (char*)d_ws;
    size_t off = 0;
    unsigned short* xpad = (unsigned short*)(ws + off); off += S1 * 2;
    const int NBR = (ws_size >= need_fused) ? 3 : 1;
    unsigned short* buf1 = (unsigned short*)(ws + off); off += S1 * 2 * NBR;
    unsigned short* buf2 = (unsigned short*)(ws + off); off += S2 * 2 * NBR;
    unsigned short* w1p  = (unsigned short*)(ws + off); off += (size_t)6 * 294912 * 2;
    unsigned short* w2p  = (unsigned short*)(ws + off); off += (size_t)3 * 294912 * 2;
    float* stats         = (float*)(ws + off);          off += (size_t)6 * 512 * 4;

    hipMemsetAsync(stats, 0, 6 * 512 * 4, stream);
    {
        int zthreads = 82432 * (1 + NBR) + 41216 * NBR;
        zero_all<<<(zthreads + 255) / 256, 256, 0, stream>>>(xpad, buf1, S1, buf2, S2, NBR);
    }
    transpose_pad<<<12800, 256, 0, stream>>>(fpn, xpad);
    pack_all<<<10368, 256, 0, stream>>>(W1[0], W1[1], W1[2], W2[0], W2[1], W2[2], w1p, w2p);

    if (NBR == 3) {
        // branch-fused: 3x blocks per dispatch, 4 big dispatches total
        conv3x3_mfma<256, 800><<<2400, 256, 0, stream>>>(
            xpad, 0, w1p, (size_t)2 * 294912, buf1, S1, stats, 1024);
        bn_apply<256, 12800><<<38400, 256, 0, stream>>>(
            buf1, S1, stats, 1024, G1[0], G1[1], G1[2], B1[0], B1[1], B1[2]);
        conv3x3_mfma<128, 400><<<1200, 256, 0, stream>>>(
            buf1, S1, w2p, (size_t)294912, buf2, S2, stats + 512, 1024);
        bn_apply<128, 6400><<<19200, 256, 0, stream>>>(
            buf2, S2, stats + 512, 1024, G2[0], G2[1], G2[2], B2[0], B2[1], B2[2]);
        head_conv_dual<<<400, 256, 0, stream>>>(buf2, w_shrink, b_shrink, w_cent, b_cent,
                                                out, out + 102400);
        head_conv<2><<<400, 256, 0, stream>>>(buf2 + S2, w_p3, b_p3, out + 204800);
        head_conv<8><<<400, 256, 0, stream>>>(buf2 + 2 * S2, w_s3, b_s3, out + 409600);
    } else {
        // sequential fallback if workspace is too small
        for (int br = 0; br < 3; ++br) {
            conv3x3_mfma<256, 800><<<800, 256, 0, stream>>>(
                xpad, 0, w1p + (size_t)br * 2 * 294912, 0, buf1, 0, stats + br * 1024, 0);
            bn_apply<256, 12800><<<12800, 256, 0, stream>>>(
                buf1, 0, stats + br * 1024, 0, G1[br], G1[br], G1[br], B1[br], B1[br], B1[br]);
            conv3x3_mfma<128, 400><<<400, 256, 0, stream>>>(
                buf1, 0, w2p + (size_t)br * 294912, 0, buf2, 0, stats + 512 + br * 1024, 0);
            bn_apply<128, 6400><<<6400, 256, 0, stream>>>(
                buf2, 0, stats + 512 + br * 1024, 0, G2[br], G2[br], G2[br], B2[br], B2[br], B2[br]);
            if (br == 0) {
                head_conv_dual<<<400, 256, 0, stream>>>(buf2, w_shrink, b_shrink, w_cent, b_cent,
                                                        out, out + 102400);
            } else if (br == 1) {
                head_conv<2><<<400, 256, 0, stream>>>(buf2, w_p3, b_p3, out + 204800);
            } else {
                head_conv<8><<<400, 256, 0, stream>>>(buf2, w_s3, b_s3, out + 409600);
            }
        }
    }
}

// Round 5
// 1767.738 us; speedup vs baseline: 3.2741x; 3.2741x over previous
//
#include <hip/hip_runtime.h>

typedef short bf16x8 __attribute__((ext_vector_type(8)));
typedef float f32x4 __attribute__((ext_vector_type(4)));

__device__ __forceinline__ float bf2f(unsigned short u) {
    union { unsigned int i; float f; } c; c.i = ((unsigned int)u) << 16; return c.f;
}
__device__ __forceinline__ unsigned short f2bf(float f) {
    union { float f; unsigned int i; } c; c.f = f;
    unsigned int u = c.i;
    u += 0x7fffu + ((u >> 16) & 1u);          // round-to-nearest-even
    return (unsigned short)(u >> 16);
}

// async global->LDS, 16B per lane; mapping must be wave-uniform base + lane*16
__device__ __forceinline__ void gload_lds16(const unsigned short* g, unsigned short* l) {
    __builtin_amdgcn_global_load_lds(
        (const __attribute__((address_space(1))) void*)g,
        (__attribute__((address_space(3))) void*)l, 16, 0, 0);
}

// ---------------------------------------------------------------------------
// fpn fp32 NCHW [4][256][160][160] -> bf16 NHWC padded [4][162][162][256]
__global__ void transpose_pad(const float* __restrict__ x, unsigned short* __restrict__ xpad) {
    int idx = blockIdx.x * 256 + threadIdx.x;       // 3,276,800 exact
    int w = idx % 160; int t = idx / 160;
    int cv = t % 32;   t /= 32;
    int h = t % 160;   int n = t / 160;
    const float* src = x + (((size_t)(n * 256 + cv * 8) * 160 + h) * 160 + w);
    unsigned short us[8];
#pragma unroll
    for (int k = 0; k < 8; ++k) us[k] = f2bf(src[(size_t)k * 25600]);
    uint4 o;
    o.x = (unsigned int)us[0] | ((unsigned int)us[1] << 16);
    o.y = (unsigned int)us[2] | ((unsigned int)us[3] << 16);
    o.z = (unsigned int)us[4] | ((unsigned int)us[5] << 16);
    o.w = (unsigned int)us[6] | ((unsigned int)us[7] << 16);
    *(uint4*)(xpad + ((size_t)((n * 162 + h + 1) * 162) + (w + 1)) * 256 + cv * 8) = o;
}

// zero the 1-wide border of one padded NHWC buffer
__device__ __forceinline__ void zero_border_one(unsigned short* buf, int C, int idx) {
    int CV = C >> 3;
    int cv = idx % CV; int t = idx / CV;
    int p = t % 644;   int n = t / 644;
    int h, w;
    if (p < 162)      { h = 0;   w = p; }
    else if (p < 324) { h = 161; w = p - 162; }
    else { int q = p - 324; h = 1 + (q >> 1); w = (q & 1) ? 161 : 0; }
    uint4 z = make_uint4(0u, 0u, 0u, 0u);
    *(uint4*)(buf + ((size_t)((n * 162 + h) * 162) + w) * C + cv * 8) = z;
}

// border-zero xpad + nbr buf1's (C=256) + nbr buf2's (C=128), one dispatch
__global__ void zero_all(unsigned short* __restrict__ xpad,
                         unsigned short* __restrict__ buf1, size_t s1,
                         unsigned short* __restrict__ buf2, size_t s2, int nbr) {
    int idx = blockIdx.x * 256 + threadIdx.x;
    if (idx < 82432) { zero_border_one(xpad, 256, idx); return; }
    idx -= 82432;
    int nb1 = nbr * 82432;
    if (idx < nb1) { zero_border_one(buf1 + (size_t)(idx / 82432) * s1, 256, idx % 82432); return; }
    idx -= nb1;
    int nb2 = nbr * 41216;
    if (idx < nb2) { zero_border_one(buf2 + (size_t)(idx / 41216) * s2, 128, idx % 41216); }
}

// ---------------------------------------------------------------------------
// Weight pack: fp32 OIHW [CO][256][3][3] -> per-128-co-tile fragment-order:
//   tile = 294912 shorts (576KB).
//   tp in 0..3 (taps {2tp,2tp+1}): block tp*65536; within: q(0..7)*8192;
//     idx = (g*128+co)*8+e, g 0..7: tap=2tp+(g>>2), ci=q*32+(g&3)*8+e
//   tp=4 (tap 8): block 262144, q*4096; idx=(g*128+co)*8+e, g 0..3: ci=q*32+g*8+e
// Tiles 0..5: layer1 (br=t>>1, coBase=(t&1)*128) -> w1p; 6..8: layer2 -> w2p.
__global__ void pack_all(const float* __restrict__ s0, const float* __restrict__ s1,
                         const float* __restrict__ s2, const float* __restrict__ s3,
                         const float* __restrict__ s4, const float* __restrict__ s5,
                         unsigned short* __restrict__ w1p, unsigned short* __restrict__ w2p) {
    int idx = blockIdx.x * 256 + threadIdx.x;   // 9*294912 = 2,654,208 exact
    int t = idx / 294912, r = idx - t * 294912;
    const float* src; unsigned short* dst; int coBase;
    if (t < 6) {
        int br = t >> 1;
        src = (br == 0) ? s0 : (br == 1) ? s1 : s2;
        coBase = (t & 1) * 128;
        dst = w1p + (size_t)t * 294912;
    } else {
        int br = t - 6;
        src = (br == 0) ? s3 : (br == 1) ? s4 : s5;
        coBase = 0;
        dst = w2p + (size_t)br * 294912;
    }
    int tap, ci, o;
    if (r < 262144) {
        int tp = r >> 16, rem = r & 65535;
        int q = rem >> 13, r2 = rem & 8191;
        int e = r2 & 7, gco = r2 >> 3;
        int co = gco & 127, g = gco >> 7;
        tap = tp * 2 + (g >> 2);
        ci = q * 32 + (g & 3) * 8 + e;
        o = coBase + co;
    } else {
        int rem = r - 262144;
        int q = rem >> 12, r2 = rem & 4095;
        int e = r2 & 7, gco = r2 >> 3;
        int co = gco & 127, g = gco >> 7;
        tap = 8;
        ci = q * 32 + g * 8 + e;
        o = coBase + co;
    }
    dst[r] = f2bf(src[((size_t)(o * 256 + ci)) * 9 + tap]);
}

// ---------------------------------------------------------------------------
// 3x3 conv, implicit GEMM, bf16 MFMA 16x16x32.
// R5: T3+T4 counted-vmcnt pipeline on R2's tile.
//  - single-tap A windows (8KB), A TRIPLE-buffered: window W stages A(W+2)
//    (~2 windows / ~900cyc flight); B double-buffered, staged 9 windows ahead.
//  - per window: {issue A(+2) [w==0: +B(q+1)]; 32 MFMA; s_waitcnt
//    vmcnt(8|2) lgkmcnt(0); s_barrier} -- RAW: barrier follows each wave's
//    counted wait (vmcnt is FIFO, forces all but newest stages done); WAR:
//    issues come after the barrier that closed the overwritten buffer's
//    readers. Tail windows issue harmless wrap-around dummy stages so wait
//    constants stay literal/uniform.
//  - LDS 24KB A + 48KB B = 72KB -> 2 blocks/CU; acc 128 regs -> (256,2).
template<int COT, int BPB>
__global__ __launch_bounds__(256, 2) void conv3x3_mfma(
        const unsigned short* __restrict__ xpad0, size_t xstride,
        const unsigned short* __restrict__ wpk0, size_t wstride,
        unsigned short* __restrict__ ypad0, size_t ystride,
        float* __restrict__ stats, int sstride) {
    __shared__ __align__(16) unsigned short As[3 * 4096];    // 24KB: 3 x [g4][co128][e8]
    __shared__ __align__(16) unsigned short Bs[2 * 12288];   // 48KB: 2 x [g4][pos384][e8]

    const int br = blockIdx.x / BPB;
    int bid = blockIdx.x % BPB;
    const unsigned short* xpad = xpad0 + (size_t)br * xstride;
    const unsigned short* wpk  = wpk0 + (size_t)br * wstride;
    unsigned short* ypad       = ypad0 + (size_t)br * ystride;
    float* sum   = stats + (size_t)br * sstride;
    float* sumsq = sum + 256;

    const int tid = threadIdx.x;
    const int wv = tid >> 6, lane = tid & 63;
    const int quad = lane >> 4, l15 = lane & 15;
    const int wco = wv >> 1, wsp = wv & 1;

    const int wt = bid % 5;
    const int ht = (bid / 5) % 20;
    const int n = (bid / 100) % 4;
    const int tile = bid / 400;            // 0..1 for COT=256, 0 for COT=128
    const int co0 = tile * 128;
    const int h0 = ht * 8, w0 = wt * 32;   // halo origin in padded coords

    const unsigned short* wtile = wpk + (size_t)tile * 294912;

    // B staging source offsets (6 rounds x 256 threads x 16B, clamped dupes)
    // strip: 10 rows x 34 cols, layout [g4][pos384][e8], pos = row*34+col
    int boff[6];
#pragma unroll
    for (int r = 0; r < 6; ++r) {
        int slot = r * 256 + tid;          // 0..1535
        int g = slot / 384, p = slot - g * 384;
        if (p > 339) p = 339;              // pad slots: duplicate-load, never read
        int prow = p / 34, pcol = p - prow * 34;
        boff[r] = ((n * 162 + h0 + prow) * 162 + (w0 + pcol)) * 256 + g * 8;
    }

    // b-frag base positions for this wave's 8 spatial frags
    int p0[8];
#pragma unroll
    for (int j = 0; j < 8; ++j) {
        int sp = wsp * 128 + j * 16 + l15;
        p0[j] = (sp >> 5) * 34 + (sp & 31);
    }

    f32x4 acc[4][8];
#pragma unroll
    for (int i = 0; i < 4; ++i)
#pragma unroll
        for (int j = 0; j < 8; ++j) acc[i][j] = (f32x4){0.f, 0.f, 0.f, 0.f};

    // stage one tap's A chunk (8KB) into As buffer ab; 2 vmem insts/wave
    auto stageA = [&](int tq, int tt, int ab) {
        const unsigned short* asrc = (tt < 8)
            ? wtile + (tt >> 1) * 65536 + tq * 8192 + (tt & 1) * 4096 + tid * 8
            : wtile + 262144 + tq * 4096 + tid * 8;
        unsigned short* dst = (unsigned short*)As + ab * 4096 + tid * 8;
        gload_lds16(asrc, dst);
        gload_lds16(asrc + 2048, dst + 2048);
    };
    // stage B strip for ci-chunk bq into Bs buffer bb; 6 vmem insts/wave
    auto stageB = [&](int bq, int bb) {
        const unsigned short* bqp = xpad + bq * 32;
        unsigned short* dst = (unsigned short*)Bs + bb * 12288;
#pragma unroll
        for (int r = 0; r < 6; ++r)
            gload_lds16(bqp + boff[r], dst + (r * 256 + tid) * 8);
    };

    // prologue: B(0), A(q0,t0), A(q0,t1); allow newest A in flight
    stageB(0, 0);
    stageA(0, 0, 0);
    stageA(0, 1, 1);
    asm volatile("s_waitcnt vmcnt(2)" ::: "memory");
    __builtin_amdgcn_s_barrier();

    for (int q = 0; q < 8; ++q) {          // ci chunk of 32
        const unsigned short* Bq = (const unsigned short*)Bs + (q & 1) * 12288;
#pragma unroll
        for (int w = 0; w < 9; ++w) {      // w == tap index
            // issue stages (A first so B is newest at w==0)
            {
                int tt = w + 2, tq = q;
                if (tt >= 9) { tt -= 9; tq = (q + 1) & 7; }   // wraps harmlessly at q=7
                stageA(tq, tt, (w + 2) % 3);
            }
            if (w == 0) stageB((q + 1) & 7, (q + 1) & 1);

            // compute tap w from As[w%3] and Bq
            const unsigned short* Ab = (const unsigned short*)As + (w % 3) * 4096;
            const int toff = (w / 3) * 34 + (w % 3);
            bf16x8 a[4];
#pragma unroll
            for (int i = 0; i < 4; ++i)
                a[i] = *(const bf16x8*)(Ab + (size_t)(quad * 128 + wco * 64 + i * 16 + l15) * 8);
#pragma unroll
            for (int jh = 0; jh < 2; ++jh) {      // two b-quartets: caps live regs
                bf16x8 b[4];
#pragma unroll
                for (int j = 0; j < 4; ++j)
                    b[j] = *(const bf16x8*)(Bq + (size_t)(quad * 384 + p0[jh * 4 + j] + toff) * 8);
#pragma unroll
                for (int i = 0; i < 4; ++i)
#pragma unroll
                    for (int j = 0; j < 4; ++j)
                        acc[i][jh * 4 + j] = __builtin_amdgcn_mfma_f32_16x16x32_bf16(
                            a[i], b[j], acc[i][jh * 4 + j], 0, 0, 0);
            }
            // counted wait (FIFO): forces everything except this window's
            // newest stages; at w<=1 the newest 8 = {A(+2):2, B(q+1):6}
            if (w <= 1) asm volatile("s_waitcnt vmcnt(8) lgkmcnt(0)" ::: "memory");
            else        asm volatile("s_waitcnt vmcnt(2) lgkmcnt(0)" ::: "memory");
            __builtin_amdgcn_s_barrier();
        }
    }
    // drain outstanding LDS-DMA before block teardown
    asm volatile("s_waitcnt vmcnt(0)" ::: "memory");

    // epilogue: store y (bf16, NHWC padded interior) + BN partial stats
#pragma unroll
    for (int i = 0; i < 4; ++i) {
        const int co_e = wco * 64 + i * 16 + quad * 4;
#pragma unroll
        for (int j = 0; j < 8; ++j) {
            const int sp = wsp * 128 + j * 16 + l15;
            const int jh = sp >> 5, jw = sp & 31;
            f32x4 v = acc[i][j];
            ushort4 pk;
            pk.x = f2bf(v[0]); pk.y = f2bf(v[1]); pk.z = f2bf(v[2]); pk.w = f2bf(v[3]);
            *(ushort4*)(ypad + ((size_t)((n * 162 + h0 + jh + 1) * 162) + (w0 + jw + 1)) * COT
                        + co0 + co_e) = pk;
        }
#pragma unroll
        for (int r = 0; r < 4; ++r) {
            float s1 = 0.f, s2 = 0.f;
#pragma unroll
            for (int j = 0; j < 8; ++j) { float v = acc[i][j][r]; s1 += v; s2 += v * v; }
#pragma unroll
            for (int m = 1; m < 16; m <<= 1) {
                s1 += __shfl_xor(s1, m, 64);
                s2 += __shfl_xor(s2, m, 64);
            }
            if (l15 == 0) {
                atomicAdd(&sum[co0 + co_e + r], s1);
                atomicAdd(&sumsq[co0 + co_e + r], s2);
            }
        }
    }
}

// ---------------------------------------------------------------------------
// fused BN finalize + in-place relu(y*scale+shift); branch-fused via BPB
template<int C, int BPB>
__global__ void bn_apply(unsigned short* __restrict__ buf0, size_t bstride,
                         const float* __restrict__ stats, int sstride,
                         const float* g0, const float* g1, const float* g2,
                         const float* be0, const float* be1, const float* be2) {
    const int br = blockIdx.x / BPB;
    unsigned short* buf = buf0 + (size_t)br * bstride;
    const float* sum = stats + (size_t)br * sstride;
    const float* sumsq = sum + 256;
    const float* gamma = (br == 0) ? g0 : (br == 1) ? g1 : g2;
    const float* beta  = (br == 0) ? be0 : (br == 1) ? be1 : be2;

    __shared__ float s_sc[C], s_sh[C];
    if (threadIdx.x < C) {
        int c = threadIdx.x;
        const float inv = 1.0f / 102400.0f;
        float m = sum[c] * inv;
        float v = sumsq[c] * inv - m * m;
        float sc = gamma[c] * rsqrtf(v + 1e-5f);
        s_sc[c] = sc;
        s_sh[c] = beta[c] - m * sc;
    }
    __syncthreads();

    constexpr int CV = C / 8;
    int idx = (blockIdx.x % BPB) * 256 + threadIdx.x;   // 4*25600*CV exact per branch
    int cv = idx % CV; int pos = idx / CV;
    int w = pos % 160; int h = (pos / 160) % 160; int n = pos / 25600;
    unsigned short* p = buf + ((size_t)((n * 162 + h + 1) * 162) + (w + 1)) * C + cv * 8;
    uint4 v = *(const uint4*)p;
    unsigned int ua[4] = {v.x, v.y, v.z, v.w};
    unsigned int ob[4];
#pragma unroll
    for (int j = 0; j < 4; ++j) {
        int c = cv * 8 + j * 2;
        float f0 = bf2f((unsigned short)(ua[j] & 0xffffu)) * s_sc[c] + s_sh[c];
        float f1 = bf2f((unsigned short)(ua[j] >> 16)) * s_sc[c + 1] + s_sh[c + 1];
        f0 = fmaxf(f0, 0.f); f1 = fmaxf(f1, 0.f);
        ob[j] = (unsigned int)f2bf(f0) | ((unsigned int)f2bf(f1) << 16);
    }
    uint4 o = make_uint4(ob[0], ob[1], ob[2], ob[3]);
    *(uint4*)p = o;
}

// ---------------------------------------------------------------------------
// head conv: z [4][162][162][128] bf16 padded -> out [4][CO][160][160] fp32 (+bias)
template<int CO>
__global__ __launch_bounds__(256) void head_conv(const unsigned short* __restrict__ z,
                                                 const float* __restrict__ w,
                                                 const float* __restrict__ bias,
                                                 float* __restrict__ out) {
    __shared__ float s_w[CO * 9 * 128];
    for (int t = threadIdx.x; t < CO * 9 * 128; t += 256) {
        int ci = t % 128; int r = t / 128;
        int tap = r % 9;  int o = r / 9;
        s_w[t] = w[((size_t)(o * 128 + ci)) * 9 + tap];
    }
    __syncthreads();

    const int pos = blockIdx.x * 256 + threadIdx.x;   // 102400 exact
    const int pw = pos % 160, ph = (pos / 160) % 160, pn = pos / 25600;
    float acc[CO];
#pragma unroll
    for (int o = 0; o < CO; ++o) acc[o] = bias[o];

#pragma unroll
    for (int dh = 0; dh < 3; ++dh)
#pragma unroll
        for (int dw = 0; dw < 3; ++dw) {
            const int tap = dh * 3 + dw;
            const unsigned short* zp = z + ((size_t)((pn * 162 + ph + dh) * 162) + (pw + dw)) * 128;
            for (int c8 = 0; c8 < 16; ++c8) {
                uint4 v = *(const uint4*)(zp + c8 * 8);
                unsigned int ua[4] = {v.x, v.y, v.z, v.w};
                float xv[8];
#pragma unroll
                for (int j = 0; j < 4; ++j) {
                    xv[2 * j]     = bf2f((unsigned short)(ua[j] & 0xffffu));
                    xv[2 * j + 1] = bf2f((unsigned short)(ua[j] >> 16));
                }
#pragma unroll
                for (int o = 0; o < CO; ++o) {
                    const float* wp = &s_w[(o * 9 + tap) * 128 + c8 * 8];
                    float4 w0 = *(const float4*)wp;
                    float4 w1 = *(const float4*)(wp + 4);
                    acc[o] = fmaf(xv[0], w0.x, acc[o]);
                    acc[o] = fmaf(xv[1], w0.y, acc[o]);
                    acc[o] = fmaf(xv[2], w0.z, acc[o]);
                    acc[o] = fmaf(xv[3], w0.w, acc[o]);
                    acc[o] = fmaf(xv[4], w1.x, acc[o]);
                    acc[o] = fmaf(xv[5], w1.y, acc[o]);
                    acc[o] = fmaf(xv[6], w1.z, acc[o]);
                    acc[o] = fmaf(xv[7], w1.w, acc[o]);
                }
            }
        }
#pragma unroll
    for (int o = 0; o < CO; ++o)
        out[((size_t)(pn * CO + o)) * 25600 + ph * 160 + pw] = acc[o];
}

// two CO=1 heads fused (shrink + centroid)
__global__ __launch_bounds__(256) void head_conv_dual(const unsigned short* __restrict__ z,
                                                      const float* __restrict__ w1, const float* __restrict__ b1,
                                                      const float* __restrict__ w2, const float* __restrict__ b2,
                                                      float* __restrict__ out1, float* __restrict__ out2) {
    __shared__ float s_w[2 * 9 * 128];
    for (int t = threadIdx.x; t < 2 * 9 * 128; t += 256) {
        int ci = t % 128; int r = t / 128;
        int tap = r % 9;  int which = r / 9;
        const float* src = which ? w2 : w1;
        s_w[t] = src[(size_t)ci * 9 + tap];
    }
    __syncthreads();

    const int pos = blockIdx.x * 256 + threadIdx.x;
    const int pw = pos % 160, ph = (pos / 160) % 160, pn = pos / 25600;
    float a1 = b1[0], a2 = b2[0];

#pragma unroll
    for (int dh = 0; dh < 3; ++dh)
#pragma unroll
        for (int dw = 0; dw < 3; ++dw) {
            const int tap = dh * 3 + dw;
            const unsigned short* zp = z + ((size_t)((pn * 162 + ph + dh) * 162) + (pw + dw)) * 128;
            for (int c8 = 0; c8 < 16; ++c8) {
                uint4 v = *(const uint4*)(zp + c8 * 8);
                unsigned int ua[4] = {v.x, v.y, v.z, v.w};
                float xv[8];
#pragma unroll
                for (int j = 0; j < 4; ++j) {
                    xv[2 * j]     = bf2f((unsigned short)(ua[j] & 0xffffu));
                    xv[2 * j + 1] = bf2f((unsigned short)(ua[j] >> 16));
                }
                const float* wp1 = &s_w[tap * 128 + c8 * 8];
                const float* wp2 = &s_w[1152 + tap * 128 + c8 * 8];
#pragma unroll
                for (int e = 0; e < 8; ++e) {
                    a1 = fmaf(xv[e], wp1[e], a1);
                    a2 = fmaf(xv[e], wp2[e], a2);
                }
            }
        }
    out1[(size_t)pn * 25600 + ph * 160 + pw] = a1;
    out2[(size_t)pn * 25600 + ph * 160 + pw] = a2;
}

// ---------------------------------------------------------------------------
extern "C" void kernel_launch(void* const* d_in, const int* in_sizes, int n_in,
                              void* d_out, int out_size, void* d_ws, size_t ws_size,
                              hipStream_t stream) {
    const float* fpn = (const float*)d_in[0];
    const float* W1[3] = {(const float*)d_in[1],  (const float*)d_in[11], (const float*)d_in[19]};
    const float* G1[3] = {(const float*)d_in[2],  (const float*)d_in[12], (const float*)d_in[20]};
    const float* B1[3] = {(const float*)d_in[3],  (const float*)d_in[13], (const float*)d_in[21]};
    const float* W2[3] = {(const float*)d_in[4],  (const float*)d_in[14], (const float*)d_in[22]};
    const float* G2[3] = {(const float*)d_in[5],  (const float*)d_in[15], (const float*)d_in[23]};
    const float* B2[3] = {(const float*)d_in[6],  (const float*)d_in[16], (const float*)d_in[24]};
    const float* w_shrink = (const float*)d_in[7];  const float* b_shrink = (const float*)d_in[8];
    const float* w_cent   = (const float*)d_in[9];  const float* b_cent   = (const float*)d_in[10];
    const float* w_p3     = (const float*)d_in[17]; const float* b_p3     = (const float*)d_in[18];
    const float* w_s3     = (const float*)d_in[25]; const float* b_s3     = (const float*)d_in[26];
    float* out = (float*)d_out;

    const size_t S1 = (size_t)4 * 162 * 162 * 256;   // shorts per buf1
    const size_t S2 = (size_t)4 * 162 * 162 * 128;   // shorts per buf2
    const size_t need_fused = S1 * 2 * 4 /*xpad+3*buf1*/ + S2 * 2 * 3
                              + (size_t)9 * 294912 * 2 + 6 * 512 * 4;

    char* ws = (char*)d_ws;
    size_t off = 0;
    unsigned short* xpad = (unsigned short*)(ws + off); off += S1 * 2;
    const int NBR = (ws_size >= need_fused) ? 3 : 1;
    unsigned short* buf1 = (unsigned short*)(ws + off); off += S1 * 2 * NBR;
    unsigned short* buf2 = (unsigned short*)(ws + off); off += S2 * 2 * NBR;
    unsigned short* w1p  = (unsigned short*)(ws + off); off += (size_t)6 * 294912 * 2;
    unsigned short* w2p  = (unsigned short*)(ws + off); off += (size_t)3 * 294912 * 2;
    float* stats         = (float*)(ws + off);          off += (size_t)6 * 512 * 4;

    hipMemsetAsync(stats, 0, 6 * 512 * 4, stream);
    {
        int zthreads = 82432 * (1 + NBR) + 41216 * NBR;
        zero_all<<<(zthreads + 255) / 256, 256, 0, stream>>>(xpad, buf1, S1, buf2, S2, NBR);
    }
    transpose_pad<<<12800, 256, 0, stream>>>(fpn, xpad);
    pack_all<<<10368, 256, 0, stream>>>(W1[0], W1[1], W1[2], W2[0], W2[1], W2[2], w1p, w2p);

    if (NBR == 3) {
        // branch-fused: 3x blocks per dispatch, 4 big dispatches total
        conv3x3_mfma<256, 800><<<2400, 256, 0, stream>>>(
            xpad, 0, w1p, (size_t)2 * 294912, buf1, S1, stats, 1024);
        bn_apply<256, 12800><<<38400, 256, 0, stream>>>(
            buf1, S1, stats, 1024, G1[0], G1[1], G1[2], B1[0], B1[1], B1[2]);
        conv3x3_mfma<128, 400><<<1200, 256, 0, stream>>>(
            buf1, S1, w2p, (size_t)294912, buf2, S2, stats + 512, 1024);
        bn_apply<128, 6400><<<19200, 256, 0, stream>>>(
            buf2, S2, stats + 512, 1024, G2[0], G2[1], G2[2], B2[0], B2[1], B2[2]);
        head_conv_dual<<<400, 256, 0, stream>>>(buf2, w_shrink, b_shrink, w_cent, b_cent,
                                                out, out + 102400);
        head_conv<2><<<400, 256, 0, stream>>>(buf2 + S2, w_p3, b_p3, out + 204800);
        head_conv<8><<<400, 256, 0, stream>>>(buf2 + 2 * S2, w_s3, b_s3, out + 409600);
    } else {
        // sequential fallback if workspace is too small
        for (int br = 0; br < 3; ++br) {
            conv3x3_mfma<256, 800><<<800, 256, 0, stream>>>(
                xpad, 0, w1p + (size_t)br * 2 * 294912, 0, buf1, 0, stats + br * 1024, 0);
            bn_apply<256, 12800><<<12800, 256, 0, stream>>>(
                buf1, 0, stats + br * 1024, 0, G1[br], G1[br], G1[br], B1[br], B1[br], B1[br]);
            conv3x3_mfma<128, 400><<<400, 256, 0, stream>>>(
                buf1, 0, w2p + (size_t)br * 294912, 0, buf2, 0, stats + 512 + br * 1024, 0);
            bn_apply<128, 6400><<<6400, 256, 0, stream>>>(
                buf2, 0, stats + 512 + br * 1024, 0, G2[br], G2[br], G2[br], B2[br], B2[br], B2[br]);
            if (br == 0) {
                head_conv_dual<<<400, 256, 0, stream>>>(buf2, w_shrink, b_shrink, w_cent, b_cent,
                                                        out, out + 102400);
            } else if (br == 1) {
                head_conv<2><<<400, 256, 0, stream>>>(buf2, w_p3, b_p3, out + 204800);
            } else {
                head_conv<8><<<400, 256, 0, stream>>>(buf2, w_s3, b_s3, out + 409600);
            }
        }
    }
}

// Round 6
// 1682.970 us; speedup vs baseline: 3.4390x; 1.0504x over previous
//
#include <hip/hip_runtime.h>

typedef short bf16x8 __attribute__((ext_vector_type(8)));
typedef float f32x4 __attribute__((ext_vector_type(4)));

__device__ __forceinline__ float bf2f(unsigned short u) {
    union { unsigned int i; float f; } c; c.i = ((unsigned int)u) << 16; return c.f;
}
__device__ __forceinline__ unsigned short f2bf(float f) {
    union { float f; unsigned int i; } c; c.f = f;
    unsigned int u = c.i;
    u += 0x7fffu + ((u >> 16) & 1u);          // round-to-nearest-even
    return (unsigned short)(u >> 16);
}

// async global->LDS, 16B per lane; mapping must be wave-uniform base + lane*16
__device__ __forceinline__ void gload_lds16(const unsigned short* g, unsigned short* l) {
    __builtin_amdgcn_global_load_lds(
        (const __attribute__((address_space(1))) void*)g,
        (__attribute__((address_space(3))) void*)l, 16, 0, 0);
}

// ---------------------------------------------------------------------------
// fpn fp32 NCHW [4][256][160][160] -> bf16 NHWC padded [4][162][162][256]
__global__ void transpose_pad(const float* __restrict__ x, unsigned short* __restrict__ xpad) {
    int idx = blockIdx.x * 256 + threadIdx.x;       // 3,276,800 exact
    int w = idx % 160; int t = idx / 160;
    int cv = t % 32;   t /= 32;
    int h = t % 160;   int n = t / 160;
    const float* src = x + (((size_t)(n * 256 + cv * 8) * 160 + h) * 160 + w);
    unsigned short us[8];
#pragma unroll
    for (int k = 0; k < 8; ++k) us[k] = f2bf(src[(size_t)k * 25600]);
    uint4 o;
    o.x = (unsigned int)us[0] | ((unsigned int)us[1] << 16);
    o.y = (unsigned int)us[2] | ((unsigned int)us[3] << 16);
    o.z = (unsigned int)us[4] | ((unsigned int)us[5] << 16);
    o.w = (unsigned int)us[6] | ((unsigned int)us[7] << 16);
    *(uint4*)(xpad + ((size_t)((n * 162 + h + 1) * 162) + (w + 1)) * 256 + cv * 8) = o;
}

// zero the 1-wide border of one padded NHWC buffer
__device__ __forceinline__ void zero_border_one(unsigned short* buf, int C, int idx) {
    int CV = C >> 3;
    int cv = idx % CV; int t = idx / CV;
    int p = t % 644;   int n = t / 644;
    int h, w;
    if (p < 162)      { h = 0;   w = p; }
    else if (p < 324) { h = 161; w = p - 162; }
    else { int q = p - 324; h = 1 + (q >> 1); w = (q & 1) ? 161 : 0; }
    uint4 z = make_uint4(0u, 0u, 0u, 0u);
    *(uint4*)(buf + ((size_t)((n * 162 + h) * 162) + w) * C + cv * 8) = z;
}

// border-zero xpad + nbr buf1's (C=256) + nbr buf2's (C=128), one dispatch
__global__ void zero_all(unsigned short* __restrict__ xpad,
                         unsigned short* __restrict__ buf1, size_t s1,
                         unsigned short* __restrict__ buf2, size_t s2, int nbr) {
    int idx = blockIdx.x * 256 + threadIdx.x;
    if (idx < 82432) { zero_border_one(xpad, 256, idx); return; }
    idx -= 82432;
    int nb1 = nbr * 82432;
    if (idx < nb1) { zero_border_one(buf1 + (size_t)(idx / 82432) * s1, 256, idx % 82432); return; }
    idx -= nb1;
    int nb2 = nbr * 41216;
    if (idx < nb2) { zero_border_one(buf2 + (size_t)(idx / 41216) * s2, 128, idx % 41216); }
}

// ---------------------------------------------------------------------------
// Weight pack: fp32 OIHW [CO][256][3][3] -> per-128-co-tile fragment-order:
//   tile = 294912 shorts (576KB).
//   tp in 0..3 (taps {2tp,2tp+1}): block tp*65536; within: q(0..7)*8192;
//     idx = (g*128+co)*8+e, g 0..7: tap=2tp+(g>>2), ci=q*32+(g&3)*8+e
//   tp=4 (tap 8): block 262144, q*4096; idx=(g*128+co)*8+e, g 0..3: ci=q*32+g*8+e
// Tiles 0..5: layer1 (br=t>>1, coBase=(t&1)*128) -> w1p; 6..8: layer2 -> w2p.
__global__ void pack_all(const float* __restrict__ s0, const float* __restrict__ s1,
                         const float* __restrict__ s2, const float* __restrict__ s3,
                         const float* __restrict__ s4, const float* __restrict__ s5,
                         unsigned short* __restrict__ w1p, unsigned short* __restrict__ w2p) {
    int idx = blockIdx.x * 256 + threadIdx.x;   // 9*294912 = 2,654,208 exact
    int t = idx / 294912, r = idx - t * 294912;
    const float* src; unsigned short* dst; int coBase;
    if (t < 6) {
        int br = t >> 1;
        src = (br == 0) ? s0 : (br == 1) ? s1 : s2;
        coBase = (t & 1) * 128;
        dst = w1p + (size_t)t * 294912;
    } else {
        int br = t - 6;
        src = (br == 0) ? s3 : (br == 1) ? s4 : s5;
        coBase = 0;
        dst = w2p + (size_t)br * 294912;
    }
    int tap, ci, o;
    if (r < 262144) {
        int tp = r >> 16, rem = r & 65535;
        int q = rem >> 13, r2 = rem & 8191;
        int e = r2 & 7, gco = r2 >> 3;
        int co = gco & 127, g = gco >> 7;
        tap = tp * 2 + (g >> 2);
        ci = q * 32 + (g & 3) * 8 + e;
        o = coBase + co;
    } else {
        int rem = r - 262144;
        int q = rem >> 12, r2 = rem & 4095;
        int e = r2 & 7, gco = r2 >> 3;
        int co = gco & 127, g = gco >> 7;
        tap = 8;
        ci = q * 32 + g * 8 + e;
        o = coBase + co;
    }
    dst[r] = f2bf(src[((size_t)(o * 256 + ci)) * 9 + tap]);
}

// ---------------------------------------------------------------------------
// 3x3 conv, implicit GEMM, bf16 MFMA 16x16x32.
// R6: issue-one-window-early ping-pong at full occupancy.
//  - 5 windows/q: {t01}{t23}{t45}{t67}{t8}; A chunk 16KB (8KB for t8) staged
//    as ONE burst per window into ping-pong As[2][16KB] at the START of the
//    PREVIOUS window -> drain at that window's end barrier is ~a full window
//    of compute after issue (vs 0 in R2). Bursts stay phase-locked across
//    blocks (preserves R2's L2 reuse / FETCH, unlike R5's fragmented stages).
//  - B ping-pong Bs[2][24KB]; B(q+1) staged at (q,w=0).
//  - ONE __syncthreads per window (41 barriers/block vs R2's 96): WAR safe
//    because a buffer's writer issues only after the barrier that ended its
//    last reader's window.
//  - LDS 32+48=80KB -> exactly 2 blocks/CU; acc 128 VGPR, (256,2).
template<int COT, int BPB>
__global__ __launch_bounds__(256, 2) void conv3x3_mfma(
        const unsigned short* __restrict__ xpad0, size_t xstride,
        const unsigned short* __restrict__ wpk0, size_t wstride,
        unsigned short* __restrict__ ypad0, size_t ystride,
        float* __restrict__ stats, int sstride) {
    __shared__ __align__(16) unsigned short As[2][8192];    // 2 x 16KB  [g8][co128][e8]
    __shared__ __align__(16) unsigned short Bs[2][12288];   // 2 x 24KB  [g4][pos384][e8]

    const int br = blockIdx.x / BPB;
    int bid = blockIdx.x % BPB;
    const unsigned short* xpad = xpad0 + (size_t)br * xstride;
    const unsigned short* wpk  = wpk0 + (size_t)br * wstride;
    unsigned short* ypad       = ypad0 + (size_t)br * ystride;
    float* sum   = stats + (size_t)br * sstride;
    float* sumsq = sum + 256;

    const int tid = threadIdx.x;
    const int wv = tid >> 6, lane = tid & 63;
    const int quad = lane >> 4, l15 = lane & 15;
    const int wco = wv >> 1, wsp = wv & 1;

    const int wt = bid % 5;
    const int ht = (bid / 5) % 20;
    const int n = (bid / 100) % 4;
    const int tile = bid / 400;            // 0..1 for COT=256, 0 for COT=128
    const int co0 = tile * 128;
    const int h0 = ht * 8, w0 = wt * 32;   // halo origin in padded coords

    const unsigned short* wtile = wpk + (size_t)tile * 294912;

    // B staging source offsets (6 rounds x 256 threads x 16B, clamped dupes)
    // strip: 10 rows x 34 cols, layout [g4][pos384][e8], pos = row*34+col
    int boff[6];
#pragma unroll
    for (int r = 0; r < 6; ++r) {
        int slot = r * 256 + tid;          // 0..1535
        int g = slot / 384, p = slot - g * 384;
        if (p > 339) p = 339;              // pad slots: duplicate-load, never read
        int prow = p / 34, pcol = p - prow * 34;
        boff[r] = ((n * 162 + h0 + prow) * 162 + (w0 + pcol)) * 256 + g * 8;
    }

    // b-frag base positions for this wave's 8 spatial frags
    int p0[8];
#pragma unroll
    for (int j = 0; j < 8; ++j) {
        int sp = wsp * 128 + j * 16 + l15;
        p0[j] = (sp >> 5) * 34 + (sp & 31);
    }

    f32x4 acc[4][8];
#pragma unroll
    for (int i = 0; i < 4; ++i)
#pragma unroll
        for (int j = 0; j < 8; ++j) acc[i][j] = (f32x4){0.f, 0.f, 0.f, 0.f};

    // stage A window (nw,q): 16KB burst (8KB for nw==4) into As[ab]
    auto stageA = [&](int aq, int nw, int ab) {
        if (nw < 4) {
            const unsigned short* asrc = wtile + nw * 65536 + aq * 8192 + tid * 8;
#pragma unroll
            for (int c = 0; c < 4; ++c)
                gload_lds16(asrc + c * 2048, &As[ab][0] + c * 2048 + tid * 8);
        } else {
            const unsigned short* asrc = wtile + 262144 + aq * 4096 + tid * 8;
#pragma unroll
            for (int c = 0; c < 2; ++c)
                gload_lds16(asrc + c * 2048, &As[ab][0] + c * 2048 + tid * 8);
        }
    };
    auto stageB = [&](int bq, int bb) {
        const unsigned short* bqp = xpad + bq * 32;
#pragma unroll
        for (int r = 0; r < 6; ++r)
            gload_lds16(bqp + boff[r], &Bs[bb][0] + (r * 256 + tid) * 8);
    };

    // prologue: B(0) and A window (q0,w0)
    stageB(0, 0);
    stageA(0, 0, 0);
    __syncthreads();

    for (int q = 0; q < 8; ++q) {          // ci chunk of 32
        const unsigned short* Bq = &Bs[q & 1][0];
#pragma unroll
        for (int w = 0; w < 5; ++w) {      // windows: {t01}{t23}{t45}{t67}{t8}
            // issue next window's A burst (and next q's B at w==0) BEFORE
            // compute; drained at this window's end barrier (~1 window later)
            if (!(q == 7 && w == 4)) {
                const int nq = (w < 4) ? q : q + 1;
                const int nw = (w < 4) ? w + 1 : 0;
                stageA(nq, nw, (q + w + 1) & 1);
            }
            if (w == 0 && q < 7) stageB(q + 1, (q + 1) & 1);

            const unsigned short* Ab = &As[(q + w) & 1][0];
#pragma unroll
            for (int ts = 0; ts < 2; ++ts) {
                if (w == 4 && ts == 1) continue;      // folds at compile time
                const int TAP = (w < 4) ? (w * 2 + ts) : 8;
                const int dh = TAP / 3, dww = TAP % 3;
                const int toff = dh * 34 + dww;
                const int g0 = (w < 4 ? ts * 4 : 0) + quad;
                bf16x8 a[4];
#pragma unroll
                for (int i = 0; i < 4; ++i)
                    a[i] = *(const bf16x8*)(Ab + (size_t)(g0 * 128 + wco * 64 + i * 16 + l15) * 8);
#pragma unroll
                for (int jh = 0; jh < 2; ++jh) {      // two b-quartets: caps live regs
                    bf16x8 b[4];
#pragma unroll
                    for (int j = 0; j < 4; ++j)
                        b[j] = *(const bf16x8*)(Bq + (size_t)(quad * 384 + p0[jh * 4 + j] + toff) * 8);
#pragma unroll
                    for (int i = 0; i < 4; ++i)
#pragma unroll
                        for (int j = 0; j < 4; ++j)
                            acc[i][jh * 4 + j] = __builtin_amdgcn_mfma_f32_16x16x32_bf16(
                                a[i], b[j], acc[i][jh * 4 + j], 0, 0, 0);
                }
            }
            __syncthreads();   // drains the early-issued stages; closes window
        }
    }

    // epilogue: store y (bf16, NHWC padded interior) + BN partial stats
#pragma unroll
    for (int i = 0; i < 4; ++i) {
        const int co_e = wco * 64 + i * 16 + quad * 4;
#pragma unroll
        for (int j = 0; j < 8; ++j) {
            const int sp = wsp * 128 + j * 16 + l15;
            const int jh = sp >> 5, jw = sp & 31;
            f32x4 v = acc[i][j];
            ushort4 pk;
            pk.x = f2bf(v[0]); pk.y = f2bf(v[1]); pk.z = f2bf(v[2]); pk.w = f2bf(v[3]);
            *(ushort4*)(ypad + ((size_t)((n * 162 + h0 + jh + 1) * 162) + (w0 + jw + 1)) * COT
                        + co0 + co_e) = pk;
        }
#pragma unroll
        for (int r = 0; r < 4; ++r) {
            float s1 = 0.f, s2 = 0.f;
#pragma unroll
            for (int j = 0; j < 8; ++j) { float v = acc[i][j][r]; s1 += v; s2 += v * v; }
#pragma unroll
            for (int m = 1; m < 16; m <<= 1) {
                s1 += __shfl_xor(s1, m, 64);
                s2 += __shfl_xor(s2, m, 64);
            }
            if (l15 == 0) {
                atomicAdd(&sum[co0 + co_e + r], s1);
                atomicAdd(&sumsq[co0 + co_e + r], s2);
            }
        }
    }
}

// ---------------------------------------------------------------------------
// fused BN finalize + in-place relu(y*scale+shift); branch-fused via BPB
template<int C, int BPB>
__global__ void bn_apply(unsigned short* __restrict__ buf0, size_t bstride,
                         const float* __restrict__ stats, int sstride,
                         const float* g0, const float* g1, const float* g2,
                         const float* be0, const float* be1, const float* be2) {
    const int br = blockIdx.x / BPB;
    unsigned short* buf = buf0 + (size_t)br * bstride;
    const float* sum = stats + (size_t)br * sstride;
    const float* sumsq = sum + 256;
    const float* gamma = (br == 0) ? g0 : (br == 1) ? g1 : g2;
    const float* beta  = (br == 0) ? be0 : (br == 1) ? be1 : be2;

    __shared__ float s_sc[C], s_sh[C];
    if (threadIdx.x < C) {
        int c = threadIdx.x;
        const float inv = 1.0f / 102400.0f;
        float m = sum[c] * inv;
        float v = sumsq[c] * inv - m * m;
        float sc = gamma[c] * rsqrtf(v + 1e-5f);
        s_sc[c] = sc;
        s_sh[c] = beta[c] - m * sc;
    }
    __syncthreads();

    constexpr int CV = C / 8;
    int idx = (blockIdx.x % BPB) * 256 + threadIdx.x;   // 4*25600*CV exact per branch
    int cv = idx % CV; int pos = idx / CV;
    int w = pos % 160; int h = (pos / 160) % 160; int n = pos / 25600;
    unsigned short* p = buf + ((size_t)((n * 162 + h + 1) * 162) + (w + 1)) * C + cv * 8;
    uint4 v = *(const uint4*)p;
    unsigned int ua[4] = {v.x, v.y, v.z, v.w};
    unsigned int ob[4];
#pragma unroll
    for (int j = 0; j < 4; ++j) {
        int c = cv * 8 + j * 2;
        float f0 = bf2f((unsigned short)(ua[j] & 0xffffu)) * s_sc[c] + s_sh[c];
        float f1 = bf2f((unsigned short)(ua[j] >> 16)) * s_sc[c + 1] + s_sh[c + 1];
        f0 = fmaxf(f0, 0.f); f1 = fmaxf(f1, 0.f);
        ob[j] = (unsigned int)f2bf(f0) | ((unsigned int)f2bf(f1) << 16);
    }
    uint4 o = make_uint4(ob[0], ob[1], ob[2], ob[3]);
    *(uint4*)p = o;
}

// ---------------------------------------------------------------------------
// head conv: z [4][162][162][128] bf16 padded -> out [4][CO][160][160] fp32 (+bias)
template<int CO>
__global__ __launch_bounds__(256) void head_conv(const unsigned short* __restrict__ z,
                                                 const float* __restrict__ w,
                                                 const float* __restrict__ bias,
                                                 float* __restrict__ out) {
    __shared__ float s_w[CO * 9 * 128];
    for (int t = threadIdx.x; t < CO * 9 * 128; t += 256) {
        int ci = t % 128; int r = t / 128;
        int tap = r % 9;  int o = r / 9;
        s_w[t] = w[((size_t)(o * 128 + ci)) * 9 + tap];
    }
    __syncthreads();

    const int pos = blockIdx.x * 256 + threadIdx.x;   // 102400 exact
    const int pw = pos % 160, ph = (pos / 160) % 160, pn = pos / 25600;
    float acc[CO];
#pragma unroll
    for (int o = 0; o < CO; ++o) acc[o] = bias[o];

#pragma unroll
    for (int dh = 0; dh < 3; ++dh)
#pragma unroll
        for (int dw = 0; dw < 3; ++dw) {
            const int tap = dh * 3 + dw;
            const unsigned short* zp = z + ((size_t)((pn * 162 + ph + dh) * 162) + (pw + dw)) * 128;
            for (int c8 = 0; c8 < 16; ++c8) {
                uint4 v = *(const uint4*)(zp + c8 * 8);
                unsigned int ua[4] = {v.x, v.y, v.z, v.w};
                float xv[8];
#pragma unroll
                for (int j = 0; j < 4; ++j) {
                    xv[2 * j]     = bf2f((unsigned short)(ua[j] & 0xffffu));
                    xv[2 * j + 1] = bf2f((unsigned short)(ua[j] >> 16));
                }
#pragma unroll
                for (int o = 0; o < CO; ++o) {
                    const float* wp = &s_w[(o * 9 + tap) * 128 + c8 * 8];
                    float4 w0 = *(const float4*)wp;
                    float4 w1 = *(const float4*)(wp + 4);
                    acc[o] = fmaf(xv[0], w0.x, acc[o]);
                    acc[o] = fmaf(xv[1], w0.y, acc[o]);
                    acc[o] = fmaf(xv[2], w0.z, acc[o]);
                    acc[o] = fmaf(xv[3], w0.w, acc[o]);
                    acc[o] = fmaf(xv[4], w1.x, acc[o]);
                    acc[o] = fmaf(xv[5], w1.y, acc[o]);
                    acc[o] = fmaf(xv[6], w1.z, acc[o]);
                    acc[o] = fmaf(xv[7], w1.w, acc[o]);
                }
            }
        }
#pragma unroll
    for (int o = 0; o < CO; ++o)
        out[((size_t)(pn * CO + o)) * 25600 + ph * 160 + pw] = acc[o];
}

// two CO=1 heads fused (shrink + centroid)
__global__ __launch_bounds__(256) void head_conv_dual(const unsigned short* __restrict__ z,
                                                      const float* __restrict__ w1, const float* __restrict__ b1,
                                                      const float* __restrict__ w2, const float* __restrict__ b2,
                                                      float* __restrict__ out1, float* __restrict__ out2) {
    __shared__ float s_w[2 * 9 * 128];
    for (int t = threadIdx.x; t < 2 * 9 * 128; t += 256) {
        int ci = t % 128; int r = t / 128;
        int tap = r % 9;  int which = r / 9;
        const float* src = which ? w2 : w1;
        s_w[t] = src[(size_t)ci * 9 + tap];
    }
    __syncthreads();

    const int pos = blockIdx.x * 256 + threadIdx.x;
    const int pw = pos % 160, ph = (pos / 160) % 160, pn = pos / 25600;
    float a1 = b1[0], a2 = b2[0];

#pragma unroll
    for (int dh = 0; dh < 3; ++dh)
#pragma unroll
        for (int dw = 0; dw < 3; ++dw) {
            const int tap = dh * 3 + dw;
            const unsigned short* zp = z + ((size_t)((pn * 162 + ph + dh) * 162) + (pw + dw)) * 128;
            for (int c8 = 0; c8 < 16; ++c8) {
                uint4 v = *(const uint4*)(zp + c8 * 8);
                unsigned int ua[4] = {v.x, v.y, v.z, v.w};
                float xv[8];
#pragma unroll
                for (int j = 0; j < 4; ++j) {
                    xv[2 * j]     = bf2f((unsigned short)(ua[j] & 0xffffu));
                    xv[2 * j + 1] = bf2f((unsigned short)(ua[j] >> 16));
                }
                const float* wp1 = &s_w[tap * 128 + c8 * 8];
                const float* wp2 = &s_w[1152 + tap * 128 + c8 * 8];
#pragma unroll
                for (int e = 0; e < 8; ++e) {
                    a1 = fmaf(xv[e], wp1[e], a1);
                    a2 = fmaf(xv[e], wp2[e], a2);
                }
            }
        }
    out1[(size_t)pn * 25600 + ph * 160 + pw] = a1;
    out2[(size_t)pn * 25600 + ph * 160 + pw] = a2;
}

// ---------------------------------------------------------------------------
extern "C" void kernel_launch(void* const* d_in, const int* in_sizes, int n_in,
                              void* d_out, int out_size, void* d_ws, size_t ws_size,
                              hipStream_t stream) {
    const float* fpn = (const float*)d_in[0];
    const float* W1[3] = {(const float*)d_in[1],  (const float*)d_in[11], (const float*)d_in[19]};
    const float* G1[3] = {(const float*)d_in[2],  (const float*)d_in[12], (const float*)d_in[20]};
    const float* B1[3] = {(const float*)d_in[3],  (const float*)d_in[13], (const float*)d_in[21]};
    const float* W2[3] = {(const float*)d_in[4],  (const float*)d_in[14], (const float*)d_in[22]};
    const float* G2[3] = {(const float*)d_in[5],  (const float*)d_in[15], (const float*)d_in[23]};
    const float* B2[3] = {(const float*)d_in[6],  (const float*)d_in[16], (const float*)d_in[24]};
    const float* w_shrink = (const float*)d_in[7];  const float* b_shrink = (const float*)d_in[8];
    const float* w_cent   = (const float*)d_in[9];  const float* b_cent   = (const float*)d_in[10];
    const float* w_p3     = (const float*)d_in[17]; const float* b_p3     = (const float*)d_in[18];
    const float* w_s3     = (const float*)d_in[25]; const float* b_s3     = (const float*)d_in[26];
    float* out = (float*)d_out;

    const size_t S1 = (size_t)4 * 162 * 162 * 256;   // shorts per buf1
    const size_t S2 = (size_t)4 * 162 * 162 * 128;   // shorts per buf2
    const size_t need_fused = S1 * 2 * 4 /*xpad+3*buf1*/ + S2 * 2 * 3
                              + (size_t)9 * 294912 * 2 + 6 * 512 * 4;

    char* ws = (char*)d_ws;
    size_t off = 0;
    unsigned short* xpad = (unsigned short*)(ws + off); off += S1 * 2;
    const int NBR = (ws_size >= need_fused) ? 3 : 1;
    unsigned short* buf1 = (unsigned short*)(ws + off); off += S1 * 2 * NBR;
    unsigned short* buf2 = (unsigned short*)(ws + off); off += S2 * 2 * NBR;
    unsigned short* w1p  = (unsigned short*)(ws + off); off += (size_t)6 * 294912 * 2;
    unsigned short* w2p  = (unsigned short*)(ws + off); off += (size_t)3 * 294912 * 2;
    float* stats         = (float*)(ws + off);          off += (size_t)6 * 512 * 4;

    hipMemsetAsync(stats, 0, 6 * 512 * 4, stream);
    {
        int zthreads = 82432 * (1 + NBR) + 41216 * NBR;
        zero_all<<<(zthreads + 255) / 256, 256, 0, stream>>>(xpad, buf1, S1, buf2, S2, NBR);
    }
    transpose_pad<<<12800, 256, 0, stream>>>(fpn, xpad);
    pack_all<<<10368, 256, 0, stream>>>(W1[0], W1[1], W1[2], W2[0], W2[1], W2[2], w1p, w2p);

    if (NBR == 3) {
        // branch-fused: 3x blocks per dispatch, 4 big dispatches total
        conv3x3_mfma<256, 800><<<2400, 256, 0, stream>>>(
            xpad, 0, w1p, (size_t)2 * 294912, buf1, S1, stats, 1024);
        bn_apply<256, 12800><<<38400, 256, 0, stream>>>(
            buf1, S1, stats, 1024, G1[0], G1[1], G1[2], B1[0], B1[1], B1[2]);
        conv3x3_mfma<128, 400><<<1200, 256, 0, stream>>>(
            buf1, S1, w2p, (size_t)294912, buf2, S2, stats + 512, 1024);
        bn_apply<128, 6400><<<19200, 256, 0, stream>>>(
            buf2, S2, stats + 512, 1024, G2[0], G2[1], G2[2], B2[0], B2[1], B2[2]);
        head_conv_dual<<<400, 256, 0, stream>>>(buf2, w_shrink, b_shrink, w_cent, b_cent,
                                                out, out + 102400);
        head_conv<2><<<400, 256, 0, stream>>>(buf2 + S2, w_p3, b_p3, out + 204800);
        head_conv<8><<<400, 256, 0, stream>>>(buf2 + 2 * S2, w_s3, b_s3, out + 409600);
    } else {
        // sequential fallback if workspace is too small
        for (int br = 0; br < 3; ++br) {
            conv3x3_mfma<256, 800><<<800, 256, 0, stream>>>(
                xpad, 0, w1p + (size_t)br * 2 * 294912, 0, buf1, 0, stats + br * 1024, 0);
            bn_apply<256, 12800><<<12800, 256, 0, stream>>>(
                buf1, 0, stats + br * 1024, 0, G1[br], G1[br], G1[br], B1[br], B1[br], B1[br]);
            conv3x3_mfma<128, 400><<<400, 256, 0, stream>>>(
                buf1, 0, w2p + (size_t)br * 294912, 0, buf2, 0, stats + 512 + br * 1024, 0);
            bn_apply<128, 6400><<<6400, 256, 0, stream>>>(
                buf2, 0, stats + 512 + br * 1024, 0, G2[br], G2[br], G2[br], B2[br], B2[br], B2[br]);
            if (br == 0) {
                head_conv_dual<<<400, 256, 0, stream>>>(buf2, w_shrink, b_shrink, w_cent, b_cent,
                                                        out, out + 102400);
            } else if (br == 1) {
                head_conv<2><<<400, 256, 0, stream>>>(buf2, w_p3, b_p3, out + 204800);
            } else {
                head_conv<8><<<400, 256, 0, stream>>>(buf2, w_s3, b_s3, out + 409600);
            }
        }
    }
}

// Round 7
// 1195.621 us; speedup vs baseline: 4.8408x; 1.4076x over previous
//
#include <hip/hip_runtime.h>

typedef short bf16x8 __attribute__((ext_vector_type(8)));
typedef float f32x4 __attribute__((ext_vector_type(4)));

__device__ __forceinline__ float bf2f(unsigned short u) {
    union { unsigned int i; float f; } c; c.i = ((unsigned int)u) << 16; return c.f;
}
__device__ __forceinline__ unsigned short f2bf(float f) {
    union { float f; unsigned int i; } c; c.f = f;
    unsigned int u = c.i;
    u += 0x7fffu + ((u >> 16) & 1u);          // round-to-nearest-even
    return (unsigned short)(u >> 16);
}

// async global->LDS, 16B per lane; mapping must be wave-uniform base + lane*16
__device__ __forceinline__ void gload_lds16(const unsigned short* g, unsigned short* l) {
    __builtin_amdgcn_global_load_lds(
        (const __attribute__((address_space(1))) void*)g,
        (__attribute__((address_space(3))) void*)l, 16, 0, 0);
}

// ---------------------------------------------------------------------------
// prep: fused {border-zero, transpose_pad, weight-pack} in one dispatch.
// All three write disjoint buffers; grid = zb + 12800 + 10368 blocks.

__device__ __forceinline__ void zero_border_one(unsigned short* buf, int C, int idx) {
    int CV = C >> 3;
    int cv = idx % CV; int t = idx / CV;
    int p = t % 644;   int n = t / 644;
    int h, w;
    if (p < 162)      { h = 0;   w = p; }
    else if (p < 324) { h = 161; w = p - 162; }
    else { int q = p - 324; h = 1 + (q >> 1); w = (q & 1) ? 161 : 0; }
    uint4 z = make_uint4(0u, 0u, 0u, 0u);
    *(uint4*)(buf + ((size_t)((n * 162 + h) * 162) + w) * C + cv * 8) = z;
}

__device__ __forceinline__ void do_zero(unsigned short* xpad,
                                        unsigned short* buf1, size_t s1,
                                        unsigned short* buf2, size_t s2, int nbr, int idx) {
    if (idx < 82432) { zero_border_one(xpad, 256, idx); return; }
    idx -= 82432;
    int nb1 = nbr * 82432;
    if (idx < nb1) { zero_border_one(buf1 + (size_t)(idx / 82432) * s1, 256, idx % 82432); return; }
    idx -= nb1;
    int nb2 = nbr * 41216;
    if (idx < nb2) { zero_border_one(buf2 + (size_t)(idx / 41216) * s2, 128, idx % 41216); }
}

__device__ __forceinline__ void do_transpose(const float* __restrict__ x,
                                             unsigned short* __restrict__ xpad, int idx) {
    int w = idx % 160; int t = idx / 160;
    int cv = t % 32;   t /= 32;
    int h = t % 160;   int n = t / 160;
    const float* src = x + (((size_t)(n * 256 + cv * 8) * 160 + h) * 160 + w);
    unsigned short us[8];
#pragma unroll
    for (int k = 0; k < 8; ++k) us[k] = f2bf(src[(size_t)k * 25600]);
    uint4 o;
    o.x = (unsigned int)us[0] | ((unsigned int)us[1] << 16);
    o.y = (unsigned int)us[2] | ((unsigned int)us[3] << 16);
    o.z = (unsigned int)us[4] | ((unsigned int)us[5] << 16);
    o.w = (unsigned int)us[6] | ((unsigned int)us[7] << 16);
    *(uint4*)(xpad + ((size_t)((n * 162 + h + 1) * 162) + (w + 1)) * 256 + cv * 8) = o;
}

// Weight pack: fp32 OIHW [CO][256][3][3] -> per-128-co-tile fragment-order
// (tile = 294912 shorts; layout documented in earlier rounds).
__device__ __forceinline__ void do_pack(const float* s0, const float* s1, const float* s2,
                                        const float* s3, const float* s4, const float* s5,
                                        unsigned short* w1p, unsigned short* w2p, int idx) {
    int t = idx / 294912, r = idx - t * 294912;
    const float* src; unsigned short* dst; int coBase;
    if (t < 6) {
        int br = t >> 1;
        src = (br == 0) ? s0 : (br == 1) ? s1 : s2;
        coBase = (t & 1) * 128;
        dst = w1p + (size_t)t * 294912;
    } else {
        int br = t - 6;
        src = (br == 0) ? s3 : (br == 1) ? s4 : s5;
        coBase = 0;
        dst = w2p + (size_t)br * 294912;
    }
    int tap, ci, o;
    if (r < 262144) {
        int tp = r >> 16, rem = r & 65535;
        int q = rem >> 13, r2 = rem & 8191;
        int e = r2 & 7, gco = r2 >> 3;
        int co = gco & 127, g = gco >> 7;
        tap = tp * 2 + (g >> 2);
        ci = q * 32 + (g & 3) * 8 + e;
        o = coBase + co;
    } else {
        int rem = r - 262144;
        int q = rem >> 12, r2 = rem & 4095;
        int e = r2 & 7, gco = r2 >> 3;
        int co = gco & 127, g = gco >> 7;
        tap = 8;
        ci = q * 32 + g * 8 + e;
        o = coBase + co;
    }
    dst[r] = f2bf(src[((size_t)(o * 256 + ci)) * 9 + tap]);
}

__global__ void prep(const float* __restrict__ fpn, unsigned short* __restrict__ xpad,
                     unsigned short* __restrict__ buf1, size_t s1,
                     unsigned short* __restrict__ buf2, size_t s2, int nbr,
                     int zb, int zcount,
                     const float* w10, const float* w11, const float* w12,
                     const float* w20, const float* w21, const float* w22,
                     unsigned short* __restrict__ w1p, unsigned short* __restrict__ w2p) {
    int bid = blockIdx.x;
    if (bid < zb) {
        int idx = bid * 256 + threadIdx.x;
        if (idx < zcount) do_zero(xpad, buf1, s1, buf2, s2, nbr, idx);
        return;
    }
    bid -= zb;
    if (bid < 12800) { do_transpose(fpn, xpad, bid * 256 + threadIdx.x); return; }
    bid -= 12800;
    do_pack(w10, w11, w12, w20, w21, w22, w1p, w2p, bid * 256 + threadIdx.x);
}

// ---------------------------------------------------------------------------
// 3x3 conv, implicit GEMM, bf16 MFMA 16x16x32.  (R2 structure, verbatim:
// measured 487/244 us; every pipelining variant regressed -- see R1/R5/R6.)
//  - wave tile 64co x 128sp (acc 128 VGPR), block 128co x 256sp.
//  - 3 windows/q ({taps0-3}{taps4-7}{tap8}); sync; stage; sync; compute.
//  - LDS 32KB A + 24KB B = 56KB, 2 blocks/CU.
template<int COT, int BPB>
__global__ __launch_bounds__(256, 2) void conv3x3_mfma(
        const unsigned short* __restrict__ xpad0, size_t xstride,
        const unsigned short* __restrict__ wpk0, size_t wstride,
        unsigned short* __restrict__ ypad0, size_t ystride,
        float* __restrict__ stats, int sstride) {
    __shared__ __align__(16) unsigned short As[16384];   // 32KB: 2 halves, each [g8][co128][e8]
    __shared__ __align__(16) unsigned short Bs[12288];   // 24KB: [g4][pos384][e8]

    const int br = blockIdx.x / BPB;
    int bid = blockIdx.x % BPB;
    const unsigned short* xpad = xpad0 + (size_t)br * xstride;
    const unsigned short* wpk  = wpk0 + (size_t)br * wstride;
    unsigned short* ypad       = ypad0 + (size_t)br * ystride;
    float* sum   = stats + (size_t)br * sstride;
    float* sumsq = sum + 256;

    const int tid = threadIdx.x;
    const int wv = tid >> 6, lane = tid & 63;
    const int quad = lane >> 4, l15 = lane & 15;
    const int wco = wv >> 1, wsp = wv & 1;

    const int wt = bid % 5;
    const int ht = (bid / 5) % 20;
    const int n = (bid / 100) % 4;
    const int tile = bid / 400;            // 0..1 for COT=256, 0 for COT=128
    const int co0 = tile * 128;
    const int h0 = ht * 8, w0 = wt * 32;   // halo origin in padded coords

    const unsigned short* wtile = wpk + (size_t)tile * 294912;

    // B staging source offsets (6 rounds of 256 threads x 16B = 24KB strip)
    // strip: 10 rows x 34 cols, layout Bs[g4][pos384][e8], pos = row*34+col
    int boff[6];
#pragma unroll
    for (int r = 0; r < 6; ++r) {
        int slot = r * 256 + tid;          // 0..1535
        int g = slot / 384, p = slot - g * 384;
        if (p > 339) p = 339;              // pad slots: duplicate-load, never read
        int prow = p / 34, pcol = p - prow * 34;
        boff[r] = ((n * 162 + h0 + prow) * 162 + (w0 + pcol)) * 256 + g * 8;
    }

    // b-frag base positions for this wave's 8 spatial frags
    int p0[8];
#pragma unroll
    for (int j = 0; j < 8; ++j) {
        int sp = wsp * 128 + j * 16 + l15;
        p0[j] = (sp >> 5) * 34 + (sp & 31);
    }

    f32x4 acc[4][8];
#pragma unroll
    for (int i = 0; i < 4; ++i)
#pragma unroll
        for (int j = 0; j < 8; ++j) acc[i][j] = (f32x4){0.f, 0.f, 0.f, 0.f};

    for (int q = 0; q < 8; ++q) {          // ci chunk of 32
#pragma unroll
        for (int w = 0; w < 3; ++w) {      // windows: taps{0-3}, {4-7}, {8}
            __syncthreads();               // prior window's LDS reads complete
            if (w == 0) {                  // B strip for this q
                const unsigned short* bq = xpad + q * 32;
#pragma unroll
                for (int r = 0; r < 6; ++r)
                    gload_lds16(bq + boff[r], (unsigned short*)Bs + (r * 256 + tid) * 8);
            }
            if (w < 2) {                   // two 16KB tap-pair blocks
#pragma unroll
                for (int h = 0; h < 2; ++h) {
                    const unsigned short* asrc = wtile + (w * 2 + h) * 65536 + q * 8192 + tid * 8;
#pragma unroll
                    for (int c = 0; c < 4; ++c)
                        gload_lds16(asrc + c * 2048,
                                    (unsigned short*)As + h * 8192 + c * 2048 + tid * 8);
                }
            } else {                       // tap 8: 8KB
                const unsigned short* asrc = wtile + 262144 + q * 4096 + tid * 8;
#pragma unroll
                for (int c = 0; c < 2; ++c)
                    gload_lds16(asrc + c * 2048, (unsigned short*)As + c * 2048 + tid * 8);
            }
            __syncthreads();               // drain DMA: tiles ready

#pragma unroll
            for (int t = 0; t < 4; ++t) {
                if (w == 2 && t >= 1) continue;       // folds at compile time
                const int TAP = (w < 2) ? (w * 4 + t) : 8;
                const int dh = TAP / 3, dw = TAP % 3;
                const int toff = dh * 34 + dw;
                const int g0 = (w < 2) ? ((t & 1) * 4 + quad) : quad;
                const unsigned short* Ab = As + ((w < 2) ? (t >> 1) * 8192 : 0);
                bf16x8 a[4];
#pragma unroll
                for (int i = 0; i < 4; ++i)
                    a[i] = *(const bf16x8*)(Ab + (size_t)(g0 * 128 + wco * 64 + i * 16 + l15) * 8);
#pragma unroll
                for (int jh = 0; jh < 2; ++jh) {      // two b-quartets: caps live regs
                    bf16x8 b[4];
#pragma unroll
                    for (int j = 0; j < 4; ++j)
                        b[j] = *(const bf16x8*)(Bs + (size_t)(quad * 384 + p0[jh * 4 + j] + toff) * 8);
#pragma unroll
                    for (int i = 0; i < 4; ++i)
#pragma unroll
                        for (int j = 0; j < 4; ++j)
                            acc[i][jh * 4 + j] = __builtin_amdgcn_mfma_f32_16x16x32_bf16(
                                a[i], b[j], acc[i][jh * 4 + j], 0, 0, 0);
                }
            }
        }
    }

    // epilogue: store y (bf16, NHWC padded interior) + BN partial stats
#pragma unroll
    for (int i = 0; i < 4; ++i) {
        const int co_l = wco * 64 + i * 16 + quad * 4;
#pragma unroll
        for (int j = 0; j < 8; ++j) {
            const int sp = wsp * 128 + j * 16 + l15;
            const int jh = sp >> 5, jw = sp & 31;
            f32x4 v = acc[i][j];
            ushort4 pk;
            pk.x = f2bf(v[0]); pk.y = f2bf(v[1]); pk.z = f2bf(v[2]); pk.w = f2bf(v[3]);
            *(ushort4*)(ypad + ((size_t)((n * 162 + h0 + jh + 1) * 162) + (w0 + jw + 1)) * COT
                        + co0 + co_l) = pk;
        }
#pragma unroll
        for (int r = 0; r < 4; ++r) {
            float s1 = 0.f, s2 = 0.f;
#pragma unroll
            for (int j = 0; j < 8; ++j) { float v = acc[i][j][r]; s1 += v; s2 += v * v; }
#pragma unroll
            for (int m = 1; m < 16; m <<= 1) {
                s1 += __shfl_xor(s1, m, 64);
                s2 += __shfl_xor(s2, m, 64);
            }
            if (l15 == 0) {
                atomicAdd(&sum[co0 + co_l + r], s1);
                atomicAdd(&sumsq[co0 + co_l + r], s2);
            }
        }
    }
}

// ---------------------------------------------------------------------------
// fused BN finalize + in-place relu(y*scale+shift); branch-fused via BPB
template<int C, int BPB>
__global__ void bn_apply(unsigned short* __restrict__ buf0, size_t bstride,
                         const float* __restrict__ stats, int sstride,
                         const float* g0, const float* g1, const float* g2,
                         const float* be0, const float* be1, const float* be2) {
    const int br = blockIdx.x / BPB;
    unsigned short* buf = buf0 + (size_t)br * bstride;
    const float* sum = stats + (size_t)br * sstride;
    const float* sumsq = sum + 256;
    const float* gamma = (br == 0) ? g0 : (br == 1) ? g1 : g2;
    const float* beta  = (br == 0) ? be0 : (br == 1) ? be1 : be2;

    __shared__ float s_sc[C], s_sh[C];
    if (threadIdx.x < C) {
        int c = threadIdx.x;
        const float inv = 1.0f / 102400.0f;
        float m = sum[c] * inv;
        float v = sumsq[c] * inv - m * m;
        float sc = gamma[c] * rsqrtf(v + 1e-5f);
        s_sc[c] = sc;
        s_sh[c] = beta[c] - m * sc;
    }
    __syncthreads();

    constexpr int CV = C / 8;
    int idx = (blockIdx.x % BPB) * 256 + threadIdx.x;   // 4*25600*CV exact per branch
    int cv = idx % CV; int pos = idx / CV;
    int w = pos % 160; int h = (pos / 160) % 160; int n = pos / 25600;
    unsigned short* p = buf + ((size_t)((n * 162 + h + 1) * 162) + (w + 1)) * C + cv * 8;
    uint4 v = *(const uint4*)p;
    unsigned int ua[4] = {v.x, v.y, v.z, v.w};
    unsigned int ob[4];
#pragma unroll
    for (int j = 0; j < 4; ++j) {
        int c = cv * 8 + j * 2;
        float f0 = bf2f((unsigned short)(ua[j] & 0xffffu)) * s_sc[c] + s_sh[c];
        float f1 = bf2f((unsigned short)(ua[j] >> 16)) * s_sc[c + 1] + s_sh[c + 1];
        f0 = fmaxf(f0, 0.f); f1 = fmaxf(f1, 0.f);
        ob[j] = (unsigned int)f2bf(f0) | ((unsigned int)f2bf(f1) << 16);
    }
    uint4 o = make_uint4(ob[0], ob[1], ob[2], ob[3]);
    *(uint4*)p = o;
}

// ---------------------------------------------------------------------------
// head conv with LDS z-staging: z [4][162][162][128] bf16 padded ->
// out [4][CO][160][160] fp32 (+bias). Per block: 8x32 output tile; stages the
// 10x34 z-strip in 4 ci-phases of 32ch (layout s_z[c8 4][pos340pad][ch8]) ->
// global z demand drops ~5.7x (was 9 taps x 16 c8 scattered reads/pixel).
template<int CO>
__global__ __launch_bounds__(256) void head_conv(const unsigned short* __restrict__ z,
                                                 const float* __restrict__ w,
                                                 const float* __restrict__ bias,
                                                 float* __restrict__ out) {
    __shared__ float s_w[CO * 9 * 128];
    __shared__ __align__(16) unsigned short s_z[1536 * 8];   // 24KB (1360 used + pad)
    for (int t = threadIdx.x; t < CO * 9 * 128; t += 256) {
        int ci = t % 128; int r = t / 128;
        int tap = r % 9;  int o = r / 9;
        s_w[t] = w[((size_t)(o * 128 + ci)) * 9 + tap];
    }

    const int bid = blockIdx.x;                       // 400 exact
    const int wt = bid % 5, ht = (bid / 5) % 20, n = bid / 100;
    const int h0 = ht * 8, w0 = wt * 32;
    const int tid = threadIdx.x;

    // staging offsets: 1360 slots = [c8 0..3][pos 0..339], 6 rounds w/ clamp
    int zoff[6];
#pragma unroll
    for (int r = 0; r < 6; ++r) {
        int slot = r * 256 + tid;
        if (slot > 1359) slot = 1359;
        int c8 = slot / 340, pos = slot - c8 * 340;
        int prow = pos / 34, pcol = pos - prow * 34;
        zoff[r] = ((n * 162 + h0 + prow) * 162 + (w0 + pcol)) * 128 + c8 * 8;
    }
    const int prow_t = tid >> 5, pcol_t = tid & 31;   // output pixel in tile

    float acc[CO];
#pragma unroll
    for (int o = 0; o < CO; ++o) acc[o] = bias[o];

    for (int ph = 0; ph < 4; ++ph) {                  // ci phases of 32
        __syncthreads();                              // prior phase reads done (and s_w ready)
#pragma unroll
        for (int r = 0; r < 6; ++r)
            gload_lds16(z + zoff[r] + ph * 32, (unsigned short*)s_z + (r * 256 + tid) * 8);
        __syncthreads();                              // drain DMA

#pragma unroll
        for (int dh = 0; dh < 3; ++dh)
#pragma unroll
            for (int dw = 0; dw < 3; ++dw) {
                const int tap = dh * 3 + dw;
                const int pos = (prow_t + dh) * 34 + pcol_t + dw;
#pragma unroll
                for (int c8 = 0; c8 < 4; ++c8) {
                    uint4 v = *(const uint4*)(s_z + (size_t)(c8 * 340 + pos) * 8);
                    unsigned int ua[4] = {v.x, v.y, v.z, v.w};
                    float xv[8];
#pragma unroll
                    for (int j = 0; j < 4; ++j) {
                        xv[2 * j]     = bf2f((unsigned short)(ua[j] & 0xffffu));
                        xv[2 * j + 1] = bf2f((unsigned short)(ua[j] >> 16));
                    }
#pragma unroll
                    for (int o = 0; o < CO; ++o) {
                        const float* wp = &s_w[(o * 9 + tap) * 128 + ph * 32 + c8 * 8];
                        float4 w0v = *(const float4*)wp;
                        float4 w1v = *(const float4*)(wp + 4);
                        acc[o] = fmaf(xv[0], w0v.x, acc[o]);
                        acc[o] = fmaf(xv[1], w0v.y, acc[o]);
                        acc[o] = fmaf(xv[2], w0v.z, acc[o]);
                        acc[o] = fmaf(xv[3], w0v.w, acc[o]);
                        acc[o] = fmaf(xv[4], w1v.x, acc[o]);
                        acc[o] = fmaf(xv[5], w1v.y, acc[o]);
                        acc[o] = fmaf(xv[6], w1v.z, acc[o]);
                        acc[o] = fmaf(xv[7], w1v.w, acc[o]);
                    }
                }
            }
    }
    const int pw = w0 + pcol_t, phh = h0 + prow_t;
#pragma unroll
    for (int o = 0; o < CO; ++o)
        out[((size_t)(n * CO + o)) * 25600 + phh * 160 + pw] = acc[o];
}

// two CO=1 heads fused (shrink + centroid), same z-staging
__global__ __launch_bounds__(256) void head_conv_dual(const unsigned short* __restrict__ z,
                                                      const float* __restrict__ w1, const float* __restrict__ b1,
                                                      const float* __restrict__ w2, const float* __restrict__ b2,
                                                      float* __restrict__ out1, float* __restrict__ out2) {
    __shared__ float s_w[2 * 9 * 128];
    __shared__ __align__(16) unsigned short s_z[1536 * 8];   // 24KB
    for (int t = threadIdx.x; t < 2 * 9 * 128; t += 256) {
        int ci = t % 128; int r = t / 128;
        int tap = r % 9;  int which = r / 9;
        const float* src = which ? w2 : w1;
        s_w[t] = src[(size_t)ci * 9 + tap];
    }

    const int bid = blockIdx.x;
    const int wt = bid % 5, ht = (bid / 5) % 20, n = bid / 100;
    const int h0 = ht * 8, w0 = wt * 32;
    const int tid = threadIdx.x;

    int zoff[6];
#pragma unroll
    for (int r = 0; r < 6; ++r) {
        int slot = r * 256 + tid;
        if (slot > 1359) slot = 1359;
        int c8 = slot / 340, pos = slot - c8 * 340;
        int prow = pos / 34, pcol = pos - prow * 34;
        zoff[r] = ((n * 162 + h0 + prow) * 162 + (w0 + pcol)) * 128 + c8 * 8;
    }
    const int prow_t = tid >> 5, pcol_t = tid & 31;

    float a1 = b1[0], a2 = b2[0];

    for (int ph = 0; ph < 4; ++ph) {
        __syncthreads();
#pragma unroll
        for (int r = 0; r < 6; ++r)
            gload_lds16(z + zoff[r] + ph * 32, (unsigned short*)s_z + (r * 256 + tid) * 8);
        __syncthreads();

#pragma unroll
        for (int dh = 0; dh < 3; ++dh)
#pragma unroll
            for (int dw = 0; dw < 3; ++dw) {
                const int tap = dh * 3 + dw;
                const int pos = (prow_t + dh) * 34 + pcol_t + dw;
#pragma unroll
                for (int c8 = 0; c8 < 4; ++c8) {
                    uint4 v = *(const uint4*)(s_z + (size_t)(c8 * 340 + pos) * 8);
                    unsigned int ua[4] = {v.x, v.y, v.z, v.w};
                    float xv[8];
#pragma unroll
                    for (int j = 0; j < 4; ++j) {
                        xv[2 * j]     = bf2f((unsigned short)(ua[j] & 0xffffu));
                        xv[2 * j + 1] = bf2f((unsigned short)(ua[j] >> 16));
                    }
                    const float* wp1 = &s_w[tap * 128 + ph * 32 + c8 * 8];
                    const float* wp2 = &s_w[1152 + tap * 128 + ph * 32 + c8 * 8];
#pragma unroll
                    for (int e = 0; e < 8; ++e) {
                        a1 = fmaf(xv[e], wp1[e], a1);
                        a2 = fmaf(xv[e], wp2[e], a2);
                    }
                }
            }
    }
    const int pw = w0 + pcol_t, phh = h0 + prow_t;
    out1[(size_t)n * 25600 + phh * 160 + pw] = a1;
    out2[(size_t)n * 25600 + phh * 160 + pw] = a2;
}

// ---------------------------------------------------------------------------
extern "C" void kernel_launch(void* const* d_in, const int* in_sizes, int n_in,
                              void* d_out, int out_size, void* d_ws, size_t ws_size,
                              hipStream_t stream) {
    const float* fpn = (const float*)d_in[0];
    const float* W1[3] = {(const float*)d_in[1],  (const float*)d_in[11], (const float*)d_in[19]};
    const float* G1[3] = {(const float*)d_in[2],  (const float*)d_in[12], (const float*)d_in[20]};
    const float* B1[3] = {(const float*)d_in[3],  (const float*)d_in[13], (const float*)d_in[21]};
    const float* W2[3] = {(const float*)d_in[4],  (const float*)d_in[14], (const float*)d_in[22]};
    const float* G2[3] = {(const float*)d_in[5],  (const float*)d_in[15], (const float*)d_in[23]};
    const float* B2[3] = {(const float*)d_in[6],  (const float*)d_in[16], (const float*)d_in[24]};
    const float* w_shrink = (const float*)d_in[7];  const float* b_shrink = (const float*)d_in[8];
    const float* w_cent   = (const float*)d_in[9];  const float* b_cent   = (const float*)d_in[10];
    const float* w_p3     = (const float*)d_in[17]; const float* b_p3     = (const float*)d_in[18];
    const float* w_s3     = (const float*)d_in[25]; const float* b_s3     = (const float*)d_in[26];
    float* out = (float*)d_out;

    const size_t S1 = (size_t)4 * 162 * 162 * 256;   // shorts per buf1
    const size_t S2 = (size_t)4 * 162 * 162 * 128;   // shorts per buf2
    const size_t need_fused = S1 * 2 * 4 /*xpad+3*buf1*/ + S2 * 2 * 3
                              + (size_t)9 * 294912 * 2 + 6 * 512 * 4;

    char* ws = (char*)d_ws;
    size_t off = 0;
    unsigned short* xpad = (unsigned short*)(ws + off); off += S1 * 2;
    const int NBR = (ws_size >= need_fused) ? 3 : 1;
    unsigned short* buf1 = (unsigned short*)(ws + off); off += S1 * 2 * NBR;
    unsigned short* buf2 = (unsigned short*)(ws + off); off += S2 * 2 * NBR;
    unsigned short* w1p  = (unsigned short*)(ws + off); off += (size_t)6 * 294912 * 2;
    unsigned short* w2p  = (unsigned short*)(ws + off); off += (size_t)3 * 294912 * 2;
    float* stats         = (float*)(ws + off);          off += (size_t)6 * 512 * 4;

    hipMemsetAsync(stats, 0, 6 * 512 * 4, stream);
    {
        int zcount = 82432 * (1 + NBR) + 41216 * NBR;
        int zb = (zcount + 255) / 256;
        prep<<<zb + 12800 + 10368, 256, 0, stream>>>(
            fpn, xpad, buf1, S1, buf2, S2, NBR, zb, zcount,
            W1[0], W1[1], W1[2], W2[0], W2[1], W2[2], w1p, w2p);
    }

    if (NBR == 3) {
        // branch-fused: 3x blocks per dispatch
        conv3x3_mfma<256, 800><<<2400, 256, 0, stream>>>(
            xpad, 0, w1p, (size_t)2 * 294912, buf1, S1, stats, 1024);
        bn_apply<256, 12800><<<38400, 256, 0, stream>>>(
            buf1, S1, stats, 1024, G1[0], G1[1], G1[2], B1[0], B1[1], B1[2]);
        conv3x3_mfma<128, 400><<<1200, 256, 0, stream>>>(
            buf1, S1, w2p, (size_t)294912, buf2, S2, stats + 512, 1024);
        bn_apply<128, 6400><<<19200, 256, 0, stream>>>(
            buf2, S2, stats + 512, 1024, G2[0], G2[1], G2[2], B2[0], B2[1], B2[2]);
        head_conv_dual<<<400, 256, 0, stream>>>(buf2, w_shrink, b_shrink, w_cent, b_cent,
                                                out, out + 102400);
        head_conv<2><<<400, 256, 0, stream>>>(buf2 + S2, w_p3, b_p3, out + 204800);
        head_conv<8><<<400, 256, 0, stream>>>(buf2 + 2 * S2, w_s3, b_s3, out + 409600);
    } else {
        // sequential fallback if workspace is too small
        for (int br = 0; br < 3; ++br) {
            conv3x3_mfma<256, 800><<<800, 256, 0, stream>>>(
                xpad, 0, w1p + (size_t)br * 2 * 294912, 0, buf1, 0, stats + br * 1024, 0);
            bn_apply<256, 12800><<<12800, 256, 0, stream>>>(
                buf1, 0, stats + br * 1024, 0, G1[br], G1[br], G1[br], B1[br], B1[br], B1[br]);
            conv3x3_mfma<128, 400><<<400, 256, 0, stream>>>(
                buf1, 0, w2p + (size_t)br * 294912, 0, buf2, 0, stats + 512 + br * 1024, 0);
            bn_apply<128, 6400><<<6400, 256, 0, stream>>>(
                buf2, 0, stats + 512 + br * 1024, 0, G2[br], G2[br], G2[br], B2[br], B2[br], B2[br]);
            if (br == 0) {
                head_conv_dual<<<400, 256, 0, stream>>>(buf2, w_shrink, b_shrink, w_cent, b_cent,
                                                        out, out + 102400);
            } else if (br == 1) {
                head_conv<2><<<400, 256, 0, stream>>>(buf2, w_p3, b_p3, out + 204800);
            } else {
                head_conv<8><<<400, 256, 0, stream>>>(buf2, w_s3, b_s3, out + 409600);
            }
        }
    }
}

// Round 8
// 1181.318 us; speedup vs baseline: 4.8994x; 1.0121x over previous
//
#include <hip/hip_runtime.h>

typedef short bf16x8 __attribute__((ext_vector_type(8)));
typedef float f32x4 __attribute__((ext_vector_type(4)));

__device__ __forceinline__ float bf2f(unsigned short u) {
    union { unsigned int i; float f; } c; c.i = ((unsigned int)u) << 16; return c.f;
}
__device__ __forceinline__ unsigned short f2bf(float f) {
    union { float f; unsigned int i; } c; c.f = f;
    unsigned int u = c.i;
    u += 0x7fffu + ((u >> 16) & 1u);          // round-to-nearest-even
    return (unsigned short)(u >> 16);
}

// async global->LDS, 16B per lane; mapping must be wave-uniform base + lane*16
__device__ __forceinline__ void gload_lds16(const unsigned short* g, unsigned short* l) {
    __builtin_amdgcn_global_load_lds(
        (const __attribute__((address_space(1))) void*)g,
        (__attribute__((address_space(3))) void*)l, 16, 0, 0);
}

// ---------------------------------------------------------------------------
// prep: fused {border-zero, transpose_pad, weight-pack} in one dispatch.

__device__ __forceinline__ void zero_border_one(unsigned short* buf, int C, int idx) {
    int CV = C >> 3;
    int cv = idx % CV; int t = idx / CV;
    int p = t % 644;   int n = t / 644;
    int h, w;
    if (p < 162)      { h = 0;   w = p; }
    else if (p < 324) { h = 161; w = p - 162; }
    else { int q = p - 324; h = 1 + (q >> 1); w = (q & 1) ? 161 : 0; }
    uint4 z = make_uint4(0u, 0u, 0u, 0u);
    *(uint4*)(buf + ((size_t)((n * 162 + h) * 162) + w) * C + cv * 8) = z;
}

__device__ __forceinline__ void do_zero(unsigned short* xpad,
                                        unsigned short* buf1, size_t s1,
                                        unsigned short* buf2, size_t s2, int nbr, int idx) {
    if (idx < 82432) { zero_border_one(xpad, 256, idx); return; }
    idx -= 82432;
    int nb1 = nbr * 82432;
    if (idx < nb1) { zero_border_one(buf1 + (size_t)(idx / 82432) * s1, 256, idx % 82432); return; }
    idx -= nb1;
    int nb2 = nbr * 41216;
    if (idx < nb2) { zero_border_one(buf2 + (size_t)(idx / 41216) * s2, 128, idx % 41216); }
}

__device__ __forceinline__ void do_transpose(const float* __restrict__ x,
                                             unsigned short* __restrict__ xpad, int idx) {
    int w = idx % 160; int t = idx / 160;
    int cv = t % 32;   t /= 32;
    int h = t % 160;   int n = t / 160;
    const float* src = x + (((size_t)(n * 256 + cv * 8) * 160 + h) * 160 + w);
    unsigned short us[8];
#pragma unroll
    for (int k = 0; k < 8; ++k) us[k] = f2bf(src[(size_t)k * 25600]);
    uint4 o;
    o.x = (unsigned int)us[0] | ((unsigned int)us[1] << 16);
    o.y = (unsigned int)us[2] | ((unsigned int)us[3] << 16);
    o.z = (unsigned int)us[4] | ((unsigned int)us[5] << 16);
    o.w = (unsigned int)us[6] | ((unsigned int)us[7] << 16);
    *(uint4*)(xpad + ((size_t)((n * 162 + h + 1) * 162) + (w + 1)) * 256 + cv * 8) = o;
}

// Weight pack: fp32 OIHW [CO][256][3][3] -> per-128-co-tile fragment-order
// (tile = 294912 shorts; layout documented in earlier rounds).
__device__ __forceinline__ void do_pack(const float* s0, const float* s1, const float* s2,
                                        const float* s3, const float* s4, const float* s5,
                                        unsigned short* w1p, unsigned short* w2p, int idx) {
    int t = idx / 294912, r = idx - t * 294912;
    const float* src; unsigned short* dst; int coBase;
    if (t < 6) {
        int br = t >> 1;
        src = (br == 0) ? s0 : (br == 1) ? s1 : s2;
        coBase = (t & 1) * 128;
        dst = w1p + (size_t)t * 294912;
    } else {
        int br = t - 6;
        src = (br == 0) ? s3 : (br == 1) ? s4 : s5;
        coBase = 0;
        dst = w2p + (size_t)br * 294912;
    }
    int tap, ci, o;
    if (r < 262144) {
        int tp = r >> 16, rem = r & 65535;
        int q = rem >> 13, r2 = rem & 8191;
        int e = r2 & 7, gco = r2 >> 3;
        int co = gco & 127, g = gco >> 7;
        tap = tp * 2 + (g >> 2);
        ci = q * 32 + (g & 3) * 8 + e;
        o = coBase + co;
    } else {
        int rem = r - 262144;
        int q = rem >> 12, r2 = rem & 4095;
        int e = r2 & 7, gco = r2 >> 3;
        int co = gco & 127, g = gco >> 7;
        tap = 8;
        ci = q * 32 + g * 8 + e;
        o = coBase + co;
    }
    dst[r] = f2bf(src[((size_t)(o * 256 + ci)) * 9 + tap]);
}

__global__ void prep(const float* __restrict__ fpn, unsigned short* __restrict__ xpad,
                     unsigned short* __restrict__ buf1, size_t s1,
                     unsigned short* __restrict__ buf2, size_t s2, int nbr,
                     int zb, int zcount,
                     const float* w10, const float* w11, const float* w12,
                     const float* w20, const float* w21, const float* w22,
                     unsigned short* __restrict__ w1p, unsigned short* __restrict__ w2p) {
    int bid = blockIdx.x;
    if (bid < zb) {
        int idx = bid * 256 + threadIdx.x;
        if (idx < zcount) do_zero(xpad, buf1, s1, buf2, s2, nbr, idx);
        return;
    }
    bid -= zb;
    if (bid < 12800) { do_transpose(fpn, xpad, bid * 256 + threadIdx.x); return; }
    bid -= 12800;
    do_pack(w10, w11, w12, w20, w21, w22, w1p, w2p, bid * 256 + threadIdx.x);
}

// ---------------------------------------------------------------------------
// 3x3 conv, implicit GEMM, bf16 MFMA 16x16x32.
// R8: R4's small-footprint window structure (5 tap-pair windows, tightened B)
// at its NATURAL register allocation: __launch_bounds__(256,2) -> compiler
// emits ~128 VGPR (measured on this tile in R2/R7), and LDS 37.25KB admits
// 4 blocks/CU at runtime (4 x 38400B = 150KB <= 160KB; 4 waves/SIMD @128reg).
// Drains overlap 3 sibling blocks' compute (R2 had only 1).
// R4's failure was solely the (256,4) register cap -> acc spill; removed.
template<int COT, int BPB>
__global__ __launch_bounds__(256, 2) void conv3x3_mfma(
        const unsigned short* __restrict__ xpad0, size_t xstride,
        const unsigned short* __restrict__ wpk0, size_t wstride,
        unsigned short* __restrict__ ypad0, size_t ystride,
        float* __restrict__ stats, int sstride) {
    __shared__ __align__(16) unsigned short As[8192];    // 16KB: [g8][co128][e8] one tap-pair
    __shared__ __align__(16) unsigned short Bs[10880];   // 21.25KB: [g4][pos340][e8]

    const int br = blockIdx.x / BPB;
    int bid = blockIdx.x % BPB;
    const unsigned short* xpad = xpad0 + (size_t)br * xstride;
    const unsigned short* wpk  = wpk0 + (size_t)br * wstride;
    unsigned short* ypad       = ypad0 + (size_t)br * ystride;
    float* sum   = stats + (size_t)br * sstride;
    float* sumsq = sum + 256;

    const int tid = threadIdx.x;
    const int wv = tid >> 6, lane = tid & 63;
    const int quad = lane >> 4, l15 = lane & 15;
    const int wco = wv >> 1, wsp = wv & 1;

    const int wt = bid % 5;
    const int ht = (bid / 5) % 20;
    const int n = (bid / 100) % 4;
    const int tile = bid / 400;            // 0..1 for COT=256, 0 for COT=128
    const int co0 = tile * 128;
    const int h0 = ht * 8, w0 = wt * 32;   // halo origin in padded coords

    const unsigned short* wtile = wpk + (size_t)tile * 294912;

    // B staging source offsets: 1360 lane-slots (5 full rounds + tid<80)
    // strip: 10 rows x 34 cols, layout Bs[g4][pos340][e8], pos = row*34+col
    int boff[6];
#pragma unroll
    for (int r = 0; r < 6; ++r) {
        int slot = r * 256 + tid;          // 0..1535; only <1360 used
        if (slot > 1359) slot = 1359;
        int g = slot / 340, p = slot - g * 340;
        int prow = p / 34, pcol = p - prow * 34;
        boff[r] = ((n * 162 + h0 + prow) * 162 + (w0 + pcol)) * 256 + g * 8;
    }

    // b-frag base positions for this wave's 8 spatial frags
    int p0[8];
#pragma unroll
    for (int j = 0; j < 8; ++j) {
        int sp = wsp * 128 + j * 16 + l15;
        p0[j] = (sp >> 5) * 34 + (sp & 31);
    }

    f32x4 acc[4][8];
#pragma unroll
    for (int i = 0; i < 4; ++i)
#pragma unroll
        for (int j = 0; j < 8; ++j) acc[i][j] = (f32x4){0.f, 0.f, 0.f, 0.f};

    for (int q = 0; q < 8; ++q) {          // ci chunk of 32
#pragma unroll
        for (int w = 0; w < 5; ++w) {      // windows: {t01}{t23}{t45}{t67}{t8}
            __syncthreads();               // prior window's LDS reads complete
            if (w == 0) {                  // B strip for this q
                const unsigned short* bqp = xpad + q * 32;
#pragma unroll
                for (int r = 0; r < 5; ++r)
                    gload_lds16(bqp + boff[r], (unsigned short*)Bs + (r * 256 + tid) * 8);
                if (tid < 80)
                    gload_lds16(bqp + boff[5], (unsigned short*)Bs + (1280 + tid) * 8);
            }
            if (w < 4) {                   // one 16KB tap-pair chunk
                const unsigned short* asrc = wtile + w * 65536 + q * 8192 + tid * 8;
#pragma unroll
                for (int c = 0; c < 4; ++c)
                    gload_lds16(asrc + c * 2048, (unsigned short*)As + c * 2048 + tid * 8);
            } else {                       // tap 8: 8KB
                const unsigned short* asrc = wtile + 262144 + q * 4096 + tid * 8;
#pragma unroll
                for (int c = 0; c < 2; ++c)
                    gload_lds16(asrc + c * 2048, (unsigned short*)As + c * 2048 + tid * 8);
            }
            __syncthreads();               // drain DMA: tiles ready

#pragma unroll
            for (int ts = 0; ts < 2; ++ts) {
                if (w == 4 && ts == 1) continue;      // folds at compile time
                const int TAP = (w < 4) ? (w * 2 + ts) : 8;
                const int dh = TAP / 3, dw = TAP % 3;
                const int toff = dh * 34 + dw;
                const int g0 = (w < 4 ? ts * 4 : 0) + quad;
                bf16x8 a[4];
#pragma unroll
                for (int i = 0; i < 4; ++i)
                    a[i] = *(const bf16x8*)(As + (size_t)(g0 * 128 + wco * 64 + i * 16 + l15) * 8);
#pragma unroll
                for (int jh = 0; jh < 2; ++jh) {      // two b-quartets: caps live regs
                    bf16x8 b[4];
#pragma unroll
                    for (int j = 0; j < 4; ++j)
                        b[j] = *(const bf16x8*)(Bs + (size_t)(quad * 340 + p0[jh * 4 + j] + toff) * 8);
#pragma unroll
                    for (int i = 0; i < 4; ++i)
#pragma unroll
                        for (int j = 0; j < 4; ++j)
                            acc[i][jh * 4 + j] = __builtin_amdgcn_mfma_f32_16x16x32_bf16(
                                a[i], b[j], acc[i][jh * 4 + j], 0, 0, 0);
                }
            }
        }
    }

    // epilogue: store y (bf16, NHWC padded interior) + BN partial stats
#pragma unroll
    for (int i = 0; i < 4; ++i) {
        const int co_e = wco * 64 + i * 16 + quad * 4;
#pragma unroll
        for (int j = 0; j < 8; ++j) {
            const int sp = wsp * 128 + j * 16 + l15;
            const int jh = sp >> 5, jw = sp & 31;
            f32x4 v = acc[i][j];
            ushort4 pk;
            pk.x = f2bf(v[0]); pk.y = f2bf(v[1]); pk.z = f2bf(v[2]); pk.w = f2bf(v[3]);
            *(ushort4*)(ypad + ((size_t)((n * 162 + h0 + jh + 1) * 162) + (w0 + jw + 1)) * COT
                        + co0 + co_e) = pk;
        }
#pragma unroll
        for (int r = 0; r < 4; ++r) {
            float s1 = 0.f, s2 = 0.f;
#pragma unroll
            for (int j = 0; j < 8; ++j) { float v = acc[i][j][r]; s1 += v; s2 += v * v; }
#pragma unroll
            for (int m = 1; m < 16; m <<= 1) {
                s1 += __shfl_xor(s1, m, 64);
                s2 += __shfl_xor(s2, m, 64);
            }
            if (l15 == 0) {
                atomicAdd(&sum[co0 + co_e + r], s1);
                atomicAdd(&sumsq[co0 + co_e + r], s2);
            }
        }
    }
}

// ---------------------------------------------------------------------------
// fused BN finalize + in-place relu(y*scale+shift); branch-fused via BPB
template<int C, int BPB>
__global__ void bn_apply(unsigned short* __restrict__ buf0, size_t bstride,
                         const float* __restrict__ stats, int sstride,
                         const float* g0, const float* g1, const float* g2,
                         const float* be0, const float* be1, const float* be2) {
    const int br = blockIdx.x / BPB;
    unsigned short* buf = buf0 + (size_t)br * bstride;
    const float* sum = stats + (size_t)br * sstride;
    const float* sumsq = sum + 256;
    const float* gamma = (br == 0) ? g0 : (br == 1) ? g1 : g2;
    const float* beta  = (br == 0) ? be0 : (br == 1) ? be1 : be2;

    __shared__ float s_sc[C], s_sh[C];
    if (threadIdx.x < C) {
        int c = threadIdx.x;
        const float inv = 1.0f / 102400.0f;
        float m = sum[c] * inv;
        float v = sumsq[c] * inv - m * m;
        float sc = gamma[c] * rsqrtf(v + 1e-5f);
        s_sc[c] = sc;
        s_sh[c] = beta[c] - m * sc;
    }
    __syncthreads();

    constexpr int CV = C / 8;
    int idx = (blockIdx.x % BPB) * 256 + threadIdx.x;   // 4*25600*CV exact per branch
    int cv = idx % CV; int pos = idx / CV;
    int w = pos % 160; int h = (pos / 160) % 160; int n = pos / 25600;
    unsigned short* p = buf + ((size_t)((n * 162 + h + 1) * 162) + (w + 1)) * C + cv * 8;
    uint4 v = *(const uint4*)p;
    unsigned int ua[4] = {v.x, v.y, v.z, v.w};
    unsigned int ob[4];
#pragma unroll
    for (int j = 0; j < 4; ++j) {
        int c = cv * 8 + j * 2;
        float f0 = bf2f((unsigned short)(ua[j] & 0xffffu)) * s_sc[c] + s_sh[c];
        float f1 = bf2f((unsigned short)(ua[j] >> 16)) * s_sc[c + 1] + s_sh[c + 1];
        f0 = fmaxf(f0, 0.f); f1 = fmaxf(f1, 0.f);
        ob[j] = (unsigned int)f2bf(f0) | ((unsigned int)f2bf(f1) << 16);
    }
    uint4 o = make_uint4(ob[0], ob[1], ob[2], ob[3]);
    *(uint4*)p = o;
}

// ---------------------------------------------------------------------------
// head conv with LDS z-staging: z [4][162][162][128] bf16 padded ->
// out [4][CO][160][160] fp32 (+bias). Per block: 8x32 output tile; stages the
// 10x34 z-strip in 4 ci-phases of 32ch.
template<int CO>
__global__ __launch_bounds__(256) void head_conv(const unsigned short* __restrict__ z,
                                                 const float* __restrict__ w,
                                                 const float* __restrict__ bias,
                                                 float* __restrict__ out) {
    __shared__ float s_w[CO * 9 * 128];
    __shared__ __align__(16) unsigned short s_z[1536 * 8];   // 24KB (1360 used + pad)
    for (int t = threadIdx.x; t < CO * 9 * 128; t += 256) {
        int ci = t % 128; int r = t / 128;
        int tap = r % 9;  int o = r / 9;
        s_w[t] = w[((size_t)(o * 128 + ci)) * 9 + tap];
    }

    const int bid = blockIdx.x;                       // 400 exact
    const int wt = bid % 5, ht = (bid / 5) % 20, n = bid / 100;
    const int h0 = ht * 8, w0 = wt * 32;
    const int tid = threadIdx.x;

    int zoff[6];
#pragma unroll
    for (int r = 0; r < 6; ++r) {
        int slot = r * 256 + tid;
        if (slot > 1359) slot = 1359;
        int c8 = slot / 340, pos = slot - c8 * 340;
        int prow = pos / 34, pcol = pos - prow * 34;
        zoff[r] = ((n * 162 + h0 + prow) * 162 + (w0 + pcol)) * 128 + c8 * 8;
    }
    const int prow_t = tid >> 5, pcol_t = tid & 31;   // output pixel in tile

    float acc[CO];
#pragma unroll
    for (int o = 0; o < CO; ++o) acc[o] = bias[o];

    for (int ph = 0; ph < 4; ++ph) {                  // ci phases of 32
        __syncthreads();                              // prior phase reads done (and s_w ready)
#pragma unroll
        for (int r = 0; r < 6; ++r)
            gload_lds16(z + zoff[r] + ph * 32, (unsigned short*)s_z + (r * 256 + tid) * 8);
        __syncthreads();                              // drain DMA

#pragma unroll
        for (int dh = 0; dh < 3; ++dh)
#pragma unroll
            for (int dw = 0; dw < 3; ++dw) {
                const int tap = dh * 3 + dw;
                const int pos = (prow_t + dh) * 34 + pcol_t + dw;
#pragma unroll
                for (int c8 = 0; c8 < 4; ++c8) {
                    uint4 v = *(const uint4*)(s_z + (size_t)(c8 * 340 + pos) * 8);
                    unsigned int ua[4] = {v.x, v.y, v.z, v.w};
                    float xv[8];
#pragma unroll
                    for (int j = 0; j < 4; ++j) {
                        xv[2 * j]     = bf2f((unsigned short)(ua[j] & 0xffffu));
                        xv[2 * j + 1] = bf2f((unsigned short)(ua[j] >> 16));
                    }
#pragma unroll
                    for (int o = 0; o < CO; ++o) {
                        const float* wp = &s_w[(o * 9 + tap) * 128 + ph * 32 + c8 * 8];
                        float4 w0v = *(const float4*)wp;
                        float4 w1v = *(const float4*)(wp + 4);
                        acc[o] = fmaf(xv[0], w0v.x, acc[o]);
                        acc[o] = fmaf(xv[1], w0v.y, acc[o]);
                        acc[o] = fmaf(xv[2], w0v.z, acc[o]);
                        acc[o] = fmaf(xv[3], w0v.w, acc[o]);
                        acc[o] = fmaf(xv[4], w1v.x, acc[o]);
                        acc[o] = fmaf(xv[5], w1v.y, acc[o]);
                        acc[o] = fmaf(xv[6], w1v.z, acc[o]);
                        acc[o] = fmaf(xv[7], w1v.w, acc[o]);
                    }
                }
            }
    }
    const int pw = w0 + pcol_t, phh = h0 + prow_t;
#pragma unroll
    for (int o = 0; o < CO; ++o)
        out[((size_t)(n * CO + o)) * 25600 + phh * 160 + pw] = acc[o];
}

// two CO=1 heads fused (shrink + centroid), same z-staging
__global__ __launch_bounds__(256) void head_conv_dual(const unsigned short* __restrict__ z,
                                                      const float* __restrict__ w1, const float* __restrict__ b1,
                                                      const float* __restrict__ w2, const float* __restrict__ b2,
                                                      float* __restrict__ out1, float* __restrict__ out2) {
    __shared__ float s_w[2 * 9 * 128];
    __shared__ __align__(16) unsigned short s_z[1536 * 8];   // 24KB
    for (int t = threadIdx.x; t < 2 * 9 * 128; t += 256) {
        int ci = t % 128; int r = t / 128;
        int tap = r % 9;  int which = r / 9;
        const float* src = which ? w2 : w1;
        s_w[t] = src[(size_t)ci * 9 + tap];
    }

    const int bid = blockIdx.x;
    const int wt = bid % 5, ht = (bid / 5) % 20, n = bid / 100;
    const int h0 = ht * 8, w0 = wt * 32;
    const int tid = threadIdx.x;

    int zoff[6];
#pragma unroll
    for (int r = 0; r < 6; ++r) {
        int slot = r * 256 + tid;
        if (slot > 1359) slot = 1359;
        int c8 = slot / 340, pos = slot - c8 * 340;
        int prow = pos / 34, pcol = pos - prow * 34;
        zoff[r] = ((n * 162 + h0 + prow) * 162 + (w0 + pcol)) * 128 + c8 * 8;
    }
    const int prow_t = tid >> 5, pcol_t = tid & 31;

    float a1 = b1[0], a2 = b2[0];

    for (int ph = 0; ph < 4; ++ph) {
        __syncthreads();
#pragma unroll
        for (int r = 0; r < 6; ++r)
            gload_lds16(z + zoff[r] + ph * 32, (unsigned short*)s_z + (r * 256 + tid) * 8);
        __syncthreads();

#pragma unroll
        for (int dh = 0; dh < 3; ++dh)
#pragma unroll
            for (int dw = 0; dw < 3; ++dw) {
                const int tap = dh * 3 + dw;
                const int pos = (prow_t + dh) * 34 + pcol_t + dw;
#pragma unroll
                for (int c8 = 0; c8 < 4; ++c8) {
                    uint4 v = *(const uint4*)(s_z + (size_t)(c8 * 340 + pos) * 8);
                    unsigned int ua[4] = {v.x, v.y, v.z, v.w};
                    float xv[8];
#pragma unroll
                    for (int j = 0; j < 4; ++j) {
                        xv[2 * j]     = bf2f((unsigned short)(ua[j] & 0xffffu));
                        xv[2 * j + 1] = bf2f((unsigned short)(ua[j] >> 16));
                    }
                    const float* wp1 = &s_w[tap * 128 + ph * 32 + c8 * 8];
                    const float* wp2 = &s_w[1152 + tap * 128 + ph * 32 + c8 * 8];
#pragma unroll
                    for (int e = 0; e < 8; ++e) {
                        a1 = fmaf(xv[e], wp1[e], a1);
                        a2 = fmaf(xv[e], wp2[e], a2);
                    }
                }
            }
    }
    const int pw = w0 + pcol_t, phh = h0 + prow_t;
    out1[(size_t)n * 25600 + phh * 160 + pw] = a1;
    out2[(size_t)n * 25600 + phh * 160 + pw] = a2;
}

// ---------------------------------------------------------------------------
extern "C" void kernel_launch(void* const* d_in, const int* in_sizes, int n_in,
                              void* d_out, int out_size, void* d_ws, size_t ws_size,
                              hipStream_t stream) {
    const float* fpn = (const float*)d_in[0];
    const float* W1[3] = {(const float*)d_in[1],  (const float*)d_in[11], (const float*)d_in[19]};
    const float* G1[3] = {(const float*)d_in[2],  (const float*)d_in[12], (const float*)d_in[20]};
    const float* B1[3] = {(const float*)d_in[3],  (const float*)d_in[13], (const float*)d_in[21]};
    const float* W2[3] = {(const float*)d_in[4],  (const float*)d_in[14], (const float*)d_in[22]};
    const float* G2[3] = {(const float*)d_in[5],  (const float*)d_in[15], (const float*)d_in[23]};
    const float* B2[3] = {(const float*)d_in[6],  (const float*)d_in[16], (const float*)d_in[24]};
    const float* w_shrink = (const float*)d_in[7];  const float* b_shrink = (const float*)d_in[8];
    const float* w_cent   = (const float*)d_in[9];  const float* b_cent   = (const float*)d_in[10];
    const float* w_p3     = (const float*)d_in[17]; const float* b_p3     = (const float*)d_in[18];
    const float* w_s3     = (const float*)d_in[25]; const float* b_s3     = (const float*)d_in[26];
    float* out = (float*)d_out;

    const size_t S1 = (size_t)4 * 162 * 162 * 256;   // shorts per buf1
    const size_t S2 = (size_t)4 * 162 * 162 * 128;   // shorts per buf2
    const size_t need_fused = S1 * 2 * 4 /*xpad+3*buf1*/ + S2 * 2 * 3
                              + (size_t)9 * 294912 * 2 + 6 * 512 * 4;

    char* ws = (char*)d_ws;
    size_t off = 0;
    unsigned short* xpad = (unsigned short*)(ws + off); off += S1 * 2;
    const int NBR = (ws_size >= need_fused) ? 3 : 1;
    unsigned short* buf1 = (unsigned short*)(ws + off); off += S1 * 2 * NBR;
    unsigned short* buf2 = (unsigned short*)(ws + off); off += S2 * 2 * NBR;
    unsigned short* w1p  = (unsigned short*)(ws + off); off += (size_t)6 * 294912 * 2;
    unsigned short* w2p  = (unsigned short*)(ws + off); off += (size_t)3 * 294912 * 2;
    float* stats         = (float*)(ws + off);          off += (size_t)6 * 512 * 4;

    hipMemsetAsync(stats, 0, 6 * 512 * 4, stream);
    {
        int zcount = 82432 * (1 + NBR) + 41216 * NBR;
        int zb = (zcount + 255) / 256;
        prep<<<zb + 12800 + 10368, 256, 0, stream>>>(
            fpn, xpad, buf1, S1, buf2, S2, NBR, zb, zcount,
            W1[0], W1[1], W1[2], W2[0], W2[1], W2[2], w1p, w2p);
    }

    if (NBR == 3) {
        // branch-fused: 3x blocks per dispatch
        conv3x3_mfma<256, 800><<<2400, 256, 0, stream>>>(
            xpad, 0, w1p, (size_t)2 * 294912, buf1, S1, stats, 1024);
        bn_apply<256, 12800><<<38400, 256, 0, stream>>>(
            buf1, S1, stats, 1024, G1[0], G1[1], G1[2], B1[0], B1[1], B1[2]);
        conv3x3_mfma<128, 400><<<1200, 256, 0, stream>>>(
            buf1, S1, w2p, (size_t)294912, buf2, S2, stats + 512, 1024);
        bn_apply<128, 6400><<<19200, 256, 0, stream>>>(
            buf2, S2, stats + 512, 1024, G2[0], G2[1], G2[2], B2[0], B2[1], B2[2]);
        head_conv_dual<<<400, 256, 0, stream>>>(buf2, w_shrink, b_shrink, w_cent, b_cent,
                                                out, out + 102400);
        head_conv<2><<<400, 256, 0, stream>>>(buf2 + S2, w_p3, b_p3, out + 204800);
        head_conv<8><<<400, 256, 0, stream>>>(buf2 + 2 * S2, w_s3, b_s3, out + 409600);
    } else {
        // sequential fallback if workspace is too small
        for (int br = 0; br < 3; ++br) {
            conv3x3_mfma<256, 800><<<800, 256, 0, stream>>>(
                xpad, 0, w1p + (size_t)br * 2 * 294912, 0, buf1, 0, stats + br * 1024, 0);
            bn_apply<256, 12800><<<12800, 256, 0, stream>>>(
                buf1, 0, stats + br * 1024, 0, G1[br], G1[br], G1[br], B1[br], B1[br], B1[br]);
            conv3x3_mfma<128, 400><<<400, 256, 0, stream>>>(
                buf1, 0, w2p + (size_t)br * 294912, 0, buf2, 0, stats + 512 + br * 1024, 0);
            bn_apply<128, 6400><<<6400, 256, 0, stream>>>(
                buf2, 0, stats + 512 + br * 1024, 0, G2[br], G2[br], G2[br], B2[br], B2[br], B2[br]);
            if (br == 0) {
                head_conv_dual<<<400, 256, 0, stream>>>(buf2, w_shrink, b_shrink, w_cent, b_cent,
                                                        out, out + 102400);
            } else if (br == 1) {
                head_conv<2><<<400, 256, 0, stream>>>(buf2, w_p3, b_p3, out + 204800);
            } else {
                head_conv<8><<<400, 256, 0, stream>>>(buf2, w_s3, b_s3, out + 409600);
            }
        }
    }
}

// Round 9
// 1146.534 us; speedup vs baseline: 5.0480x; 1.0303x over previous
//
#include <hip/hip_runtime.h>

typedef short bf16x8 __attribute__((ext_vector_type(8)));
typedef float f32x4 __attribute__((ext_vector_type(4)));

__device__ __forceinline__ float bf2f(unsigned short u) {
    union { unsigned int i; float f; } c; c.i = ((unsigned int)u) << 16; return c.f;
}
__device__ __forceinline__ unsigned short f2bf(float f) {
    union { float f; unsigned int i; } c; c.f = f;
    unsigned int u = c.i;
    u += 0x7fffu + ((u >> 16) & 1u);          // round-to-nearest-even
    return (unsigned short)(u >> 16);
}

// async global->LDS, 16B per lane; mapping must be wave-uniform base + lane*16
__device__ __forceinline__ void gload_lds16(const unsigned short* g, unsigned short* l) {
    __builtin_amdgcn_global_load_lds(
        (const __attribute__((address_space(1))) void*)g,
        (__attribute__((address_space(3))) void*)l, 16, 0, 0);
}

// ---------------------------------------------------------------------------
// prep: fused {stats-zero, border-zero, transpose_pad, weight-pack}.

__device__ __forceinline__ void zero_border_one(unsigned short* buf, int C, int idx) {
    int CV = C >> 3;
    int cv = idx % CV; int t = idx / CV;
    int p = t % 644;   int n = t / 644;
    int h, w;
    if (p < 162)      { h = 0;   w = p; }
    else if (p < 324) { h = 161; w = p - 162; }
    else { int q = p - 324; h = 1 + (q >> 1); w = (q & 1) ? 161 : 0; }
    uint4 z = make_uint4(0u, 0u, 0u, 0u);
    *(uint4*)(buf + ((size_t)((n * 162 + h) * 162) + w) * C + cv * 8) = z;
}

__device__ __forceinline__ void do_zero(unsigned short* xpad,
                                        unsigned short* buf1, size_t s1,
                                        unsigned short* buf2, size_t s2, int nbr, int idx) {
    if (idx < 82432) { zero_border_one(xpad, 256, idx); return; }
    idx -= 82432;
    int nb1 = nbr * 82432;
    if (idx < nb1) { zero_border_one(buf1 + (size_t)(idx / 82432) * s1, 256, idx % 82432); return; }
    idx -= nb1;
    int nb2 = nbr * 41216;
    if (idx < nb2) { zero_border_one(buf2 + (size_t)(idx / 41216) * s2, 128, idx % 41216); }
}

__device__ __forceinline__ void do_transpose(const float* __restrict__ x,
                                             unsigned short* __restrict__ xpad, int idx) {
    int w = idx % 160; int t = idx / 160;
    int cv = t % 32;   t /= 32;
    int h = t % 160;   int n = t / 160;
    const float* src = x + (((size_t)(n * 256 + cv * 8) * 160 + h) * 160 + w);
    unsigned short us[8];
#pragma unroll
    for (int k = 0; k < 8; ++k) us[k] = f2bf(src[(size_t)k * 25600]);
    uint4 o;
    o.x = (unsigned int)us[0] | ((unsigned int)us[1] << 16);
    o.y = (unsigned int)us[2] | ((unsigned int)us[3] << 16);
    o.z = (unsigned int)us[4] | ((unsigned int)us[5] << 16);
    o.w = (unsigned int)us[6] | ((unsigned int)us[7] << 16);
    *(uint4*)(xpad + ((size_t)((n * 162 + h + 1) * 162) + (w + 1)) * 256 + cv * 8) = o;
}

// Weight pack: fp32 OIHW [CO][256][3][3] -> per-128-co-tile fragment-order
__device__ __forceinline__ void do_pack(const float* s0, const float* s1, const float* s2,
                                        const float* s3, const float* s4, const float* s5,
                                        unsigned short* w1p, unsigned short* w2p, int idx) {
    int t = idx / 294912, r = idx - t * 294912;
    const float* src; unsigned short* dst; int coBase;
    if (t < 6) {
        int br = t >> 1;
        src = (br == 0) ? s0 : (br == 1) ? s1 : s2;
        coBase = (t & 1) * 128;
        dst = w1p + (size_t)t * 294912;
    } else {
        int br = t - 6;
        src = (br == 0) ? s3 : (br == 1) ? s4 : s5;
        coBase = 0;
        dst = w2p + (size_t)br * 294912;
    }
    int tap, ci, o;
    if (r < 262144) {
        int tp = r >> 16, rem = r & 65535;
        int q = rem >> 13, r2 = rem & 8191;
        int e = r2 & 7, gco = r2 >> 3;
        int co = gco & 127, g = gco >> 7;
        tap = tp * 2 + (g >> 2);
        ci = q * 32 + (g & 3) * 8 + e;
        o = coBase + co;
    } else {
        int rem = r - 262144;
        int q = rem >> 12, r2 = rem & 4095;
        int e = r2 & 7, gco = r2 >> 3;
        int co = gco & 127, g = gco >> 7;
        tap = 8;
        ci = q * 32 + g * 8 + e;
        o = coBase + co;
    }
    dst[r] = f2bf(src[((size_t)(o * 256 + ci)) * 9 + tap]);
}

__global__ void prep(const float* __restrict__ fpn, unsigned short* __restrict__ xpad,
                     unsigned short* __restrict__ buf1, size_t s1,
                     unsigned short* __restrict__ buf2, size_t s2, int nbr,
                     int zb, int zcount, float* __restrict__ stats,
                     const float* w10, const float* w11, const float* w12,
                     const float* w20, const float* w21, const float* w22,
                     unsigned short* __restrict__ w1p, unsigned short* __restrict__ w2p) {
    int bid = blockIdx.x;
    if (bid < 3) {                         // stats zero: 3072 floats = 768 float4
        ((float4*)stats)[bid * 256 + threadIdx.x] = make_float4(0.f, 0.f, 0.f, 0.f);
        return;
    }
    bid -= 3;
    if (bid < zb) {
        int idx = bid * 256 + threadIdx.x;
        if (idx < zcount) do_zero(xpad, buf1, s1, buf2, s2, nbr, idx);
        return;
    }
    bid -= zb;
    if (bid < 12800) { do_transpose(fpn, xpad, bid * 256 + threadIdx.x); return; }
    bid -= 12800;
    do_pack(w10, w11, w12, w20, w21, w22, w1p, w2p, bid * 256 + threadIdx.x);
}

// ---------------------------------------------------------------------------
// 3x3 conv, implicit GEMM, bf16 MFMA 16x16x32.  (R2/R7 structure, verbatim:
// measured 487-494 us, 0 bank conflicts. LDS-read-bound per R8 analysis;
// frozen.)
template<int COT, int BPB>
__global__ __launch_bounds__(256, 2) void conv3x3_mfma(
        const unsigned short* __restrict__ xpad0, size_t xstride,
        const unsigned short* __restrict__ wpk0, size_t wstride,
        unsigned short* __restrict__ ypad0, size_t ystride,
        float* __restrict__ stats, int sstride) {
    __shared__ __align__(16) unsigned short As[16384];   // 32KB: 2 halves, each [g8][co128][e8]
    __shared__ __align__(16) unsigned short Bs[12288];   // 24KB: [g4][pos384][e8]

    const int br = blockIdx.x / BPB;
    int bid = blockIdx.x % BPB;
    const unsigned short* xpad = xpad0 + (size_t)br * xstride;
    const unsigned short* wpk  = wpk0 + (size_t)br * wstride;
    unsigned short* ypad       = ypad0 + (size_t)br * ystride;
    float* sum   = stats + (size_t)br * sstride;
    float* sumsq = sum + 256;

    const int tid = threadIdx.x;
    const int wv = tid >> 6, lane = tid & 63;
    const int quad = lane >> 4, l15 = lane & 15;
    const int wco = wv >> 1, wsp = wv & 1;

    const int wt = bid % 5;
    const int ht = (bid / 5) % 20;
    const int n = (bid / 100) % 4;
    const int tile = bid / 400;            // 0..1 for COT=256, 0 for COT=128
    const int co0 = tile * 128;
    const int h0 = ht * 8, w0 = wt * 32;   // halo origin in padded coords

    const unsigned short* wtile = wpk + (size_t)tile * 294912;

    int boff[6];
#pragma unroll
    for (int r = 0; r < 6; ++r) {
        int slot = r * 256 + tid;          // 0..1535
        int g = slot / 384, p = slot - g * 384;
        if (p > 339) p = 339;              // pad slots: duplicate-load, never read
        int prow = p / 34, pcol = p - prow * 34;
        boff[r] = ((n * 162 + h0 + prow) * 162 + (w0 + pcol)) * 256 + g * 8;
    }

    int p0[8];
#pragma unroll
    for (int j = 0; j < 8; ++j) {
        int sp = wsp * 128 + j * 16 + l15;
        p0[j] = (sp >> 5) * 34 + (sp & 31);
    }

    f32x4 acc[4][8];
#pragma unroll
    for (int i = 0; i < 4; ++i)
#pragma unroll
        for (int j = 0; j < 8; ++j) acc[i][j] = (f32x4){0.f, 0.f, 0.f, 0.f};

    for (int q = 0; q < 8; ++q) {          // ci chunk of 32
#pragma unroll
        for (int w = 0; w < 3; ++w) {      // windows: taps{0-3}, {4-7}, {8}
            __syncthreads();               // prior window's LDS reads complete
            if (w == 0) {                  // B strip for this q
                const unsigned short* bq = xpad + q * 32;
#pragma unroll
                for (int r = 0; r < 6; ++r)
                    gload_lds16(bq + boff[r], (unsigned short*)Bs + (r * 256 + tid) * 8);
            }
            if (w < 2) {                   // two 16KB tap-pair blocks
#pragma unroll
                for (int h = 0; h < 2; ++h) {
                    const unsigned short* asrc = wtile + (w * 2 + h) * 65536 + q * 8192 + tid * 8;
#pragma unroll
                    for (int c = 0; c < 4; ++c)
                        gload_lds16(asrc + c * 2048,
                                    (unsigned short*)As + h * 8192 + c * 2048 + tid * 8);
                }
            } else {                       // tap 8: 8KB
                const unsigned short* asrc = wtile + 262144 + q * 4096 + tid * 8;
#pragma unroll
                for (int c = 0; c < 2; ++c)
                    gload_lds16(asrc + c * 2048, (unsigned short*)As + c * 2048 + tid * 8);
            }
            __syncthreads();               // drain DMA: tiles ready

#pragma unroll
            for (int t = 0; t < 4; ++t) {
                if (w == 2 && t >= 1) continue;       // folds at compile time
                const int TAP = (w < 2) ? (w * 4 + t) : 8;
                const int dh = TAP / 3, dw = TAP % 3;
                const int toff = dh * 34 + dw;
                const int g0 = (w < 2) ? ((t & 1) * 4 + quad) : quad;
                const unsigned short* Ab = As + ((w < 2) ? (t >> 1) * 8192 : 0);
                bf16x8 a[4];
#pragma unroll
                for (int i = 0; i < 4; ++i)
                    a[i] = *(const bf16x8*)(Ab + (size_t)(g0 * 128 + wco * 64 + i * 16 + l15) * 8);
#pragma unroll
                for (int jh = 0; jh < 2; ++jh) {
                    bf16x8 b[4];
#pragma unroll
                    for (int j = 0; j < 4; ++j)
                        b[j] = *(const bf16x8*)(Bs + (size_t)(quad * 384 + p0[jh * 4 + j] + toff) * 8);
#pragma unroll
                    for (int i = 0; i < 4; ++i)
#pragma unroll
                        for (int j = 0; j < 4; ++j)
                            acc[i][jh * 4 + j] = __builtin_amdgcn_mfma_f32_16x16x32_bf16(
                                a[i], b[j], acc[i][jh * 4 + j], 0, 0, 0);
                }
            }
        }
    }

    // epilogue: store y (bf16, NHWC padded interior) + BN partial stats
#pragma unroll
    for (int i = 0; i < 4; ++i) {
        const int co_l = wco * 64 + i * 16 + quad * 4;
#pragma unroll
        for (int j = 0; j < 8; ++j) {
            const int sp = wsp * 128 + j * 16 + l15;
            const int jh = sp >> 5, jw = sp & 31;
            f32x4 v = acc[i][j];
            ushort4 pk;
            pk.x = f2bf(v[0]); pk.y = f2bf(v[1]); pk.z = f2bf(v[2]); pk.w = f2bf(v[3]);
            *(ushort4*)(ypad + ((size_t)((n * 162 + h0 + jh + 1) * 162) + (w0 + jw + 1)) * COT
                        + co0 + co_l) = pk;
        }
#pragma unroll
        for (int r = 0; r < 4; ++r) {
            float s1 = 0.f, s2 = 0.f;
#pragma unroll
            for (int j = 0; j < 8; ++j) { float v = acc[i][j][r]; s1 += v; s2 += v * v; }
#pragma unroll
            for (int m = 1; m < 16; m <<= 1) {
                s1 += __shfl_xor(s1, m, 64);
                s2 += __shfl_xor(s2, m, 64);
            }
            if (l15 == 0) {
                atomicAdd(&sum[co0 + co_l + r], s1);
                atomicAdd(&sumsq[co0 + co_l + r], s2);
            }
        }
    }
}

// ---------------------------------------------------------------------------
// fused BN finalize + in-place relu(y*scale+shift); branch-fused via BPB
template<int C, int BPB>
__global__ void bn_apply(unsigned short* __restrict__ buf0, size_t bstride,
                         const float* __restrict__ stats, int sstride,
                         const float* g0, const float* g1, const float* g2,
                         const float* be0, const float* be1, const float* be2) {
    const int br = blockIdx.x / BPB;
    unsigned short* buf = buf0 + (size_t)br * bstride;
    const float* sum = stats + (size_t)br * sstride;
    const float* sumsq = sum + 256;
    const float* gamma = (br == 0) ? g0 : (br == 1) ? g1 : g2;
    const float* beta  = (br == 0) ? be0 : (br == 1) ? be1 : be2;

    __shared__ float s_sc[C], s_sh[C];
    if (threadIdx.x < C) {
        int c = threadIdx.x;
        const float inv = 1.0f / 102400.0f;
        float m = sum[c] * inv;
        float v = sumsq[c] * inv - m * m;
        float sc = gamma[c] * rsqrtf(v + 1e-5f);
        s_sc[c] = sc;
        s_sh[c] = beta[c] - m * sc;
    }
    __syncthreads();

    constexpr int CV = C / 8;
    int idx = (blockIdx.x % BPB) * 256 + threadIdx.x;
    int cv = idx % CV; int pos = idx / CV;
    int w = pos % 160; int h = (pos / 160) % 160; int n = pos / 25600;
    unsigned short* p = buf + ((size_t)((n * 162 + h + 1) * 162) + (w + 1)) * C + cv * 8;
    uint4 v = *(const uint4*)p;
    unsigned int ua[4] = {v.x, v.y, v.z, v.w};
    unsigned int ob[4];
#pragma unroll
    for (int j = 0; j < 4; ++j) {
        int c = cv * 8 + j * 2;
        float f0 = bf2f((unsigned short)(ua[j] & 0xffffu)) * s_sc[c] + s_sh[c];
        float f1 = bf2f((unsigned short)(ua[j] >> 16)) * s_sc[c + 1] + s_sh[c + 1];
        f0 = fmaxf(f0, 0.f); f1 = fmaxf(f1, 0.f);
        ob[j] = (unsigned int)f2bf(f0) | ((unsigned int)f2bf(f1) << 16);
    }
    uint4 o = make_uint4(ob[0], ob[1], ob[2], ob[3]);
    *(uint4*)p = o;
}

// ---------------------------------------------------------------------------
// heads_all: all three head convs in ONE dispatch (1200 blocks), with BN2+ReLU
// folded in (reads RAW conv2 output + stats; bn_apply<128> pass eliminated).
// Padding semantics: positions at padded coords 0/161 must be ZERO post-BN
// (reference zero-pads AFTER bn+relu) -> per-tap edge mask.
__global__ __launch_bounds__(256) void heads_all(
        const unsigned short* __restrict__ zb, size_t zstride,
        const float* __restrict__ stats2, int sstride,
        const float* g20, const float* g21, const float* g22,
        const float* be20, const float* be21, const float* be22,
        const float* w_sh, const float* bi_sh, const float* w_ce, const float* bi_ce,
        const float* w_p3, const float* bi_p3, const float* w_s3, const float* bi_s3,
        float* __restrict__ out) {
    const int br = blockIdx.x / 400;
    const int bid = blockIdx.x % 400;
    const unsigned short* z = zb + (size_t)br * zstride;
    const float* sum   = stats2 + (size_t)br * sstride;
    const float* sumsq = sum + 256;
    const float* gamma = (br == 0) ? g20 : (br == 1) ? g21 : g22;
    const float* beta  = (br == 0) ? be20 : (br == 1) ? be21 : be22;

    __shared__ float s_sc[128], s_sh[128];
    __shared__ float s_w[8 * 9 * 128];                       // 36KB (max CO=8)
    __shared__ __align__(16) unsigned short s_z[1536 * 8];   // 24KB

    const int tid = threadIdx.x;
    if (tid < 128) {
        const float inv = 1.0f / 102400.0f;
        float m = sum[tid] * inv;
        float v = sumsq[tid] * inv - m * m;
        float sc = gamma[tid] * rsqrtf(v + 1e-5f);
        s_sc[tid] = sc;
        s_sh[tid] = beta[tid] - m * sc;
    }
    // stage weights (branch-uniform)
    if (br == 0) {
        for (int t = tid; t < 2 * 1152; t += 256) {
            int ci = t % 128; int r = t / 128;
            int tap = r % 9;  int which = r / 9;
            const float* src = which ? w_ce : w_sh;
            s_w[t] = src[(size_t)ci * 9 + tap];
        }
    } else {
        const float* wsrc = (br == 1) ? w_p3 : w_s3;
        const int nco = (br == 1) ? 2 : 8;
        for (int t = tid; t < nco * 1152; t += 256) {
            int ci = t % 128; int r = t / 128;
            int tap = r % 9;  int o = r / 9;
            s_w[t] = wsrc[((size_t)(o * 128 + ci)) * 9 + tap];
        }
    }

    const int wt = bid % 5, ht = (bid / 5) % 20, n = bid / 100;
    const int h0 = ht * 8, w0 = wt * 32;

    int zoff[6];
#pragma unroll
    for (int r = 0; r < 6; ++r) {
        int slot = r * 256 + tid;
        if (slot > 1359) slot = 1359;
        int c8 = slot / 340, pos = slot - c8 * 340;
        int prow = pos / 34, pcol = pos - prow * 34;
        zoff[r] = ((n * 162 + h0 + prow) * 162 + (w0 + pcol)) * 128 + c8 * 8;
    }
    const int prow_t = tid >> 5, pcol_t = tid & 31;

    float acc[8];
#pragma unroll
    for (int o = 0; o < 8; ++o) acc[o] = 0.f;

    for (int ph = 0; ph < 4; ++ph) {                  // ci phases of 32
        __syncthreads();
#pragma unroll
        for (int r = 0; r < 6; ++r)
            gload_lds16(z + zoff[r] + ph * 32, (unsigned short*)s_z + (r * 256 + tid) * 8);
        __syncthreads();

#pragma unroll
        for (int dh = 0; dh < 3; ++dh)
#pragma unroll
            for (int dw = 0; dw < 3; ++dw) {
                const int tap = dh * 3 + dw;
                const int pos = (prow_t + dh) * 34 + pcol_t + dw;
                const int hh = h0 + prow_t + dh, ww = w0 + pcol_t + dw;
                const bool edge = (hh == 0) | (hh == 161) | (ww == 0) | (ww == 161);
#pragma unroll
                for (int c8 = 0; c8 < 4; ++c8) {
                    uint4 v = *(const uint4*)(s_z + (size_t)(c8 * 340 + pos) * 8);
                    unsigned int ua[4] = {v.x, v.y, v.z, v.w};
                    float zv[8];
#pragma unroll
                    for (int j = 0; j < 4; ++j) {
                        int c = ph * 32 + c8 * 8 + 2 * j;
                        float x0 = bf2f((unsigned short)(ua[j] & 0xffffu));
                        float x1 = bf2f((unsigned short)(ua[j] >> 16));
                        float y0 = fmaxf(x0 * s_sc[c] + s_sh[c], 0.f);
                        float y1 = fmaxf(x1 * s_sc[c + 1] + s_sh[c + 1], 0.f);
                        zv[2 * j]     = edge ? 0.f : y0;
                        zv[2 * j + 1] = edge ? 0.f : y1;
                    }
                    if (br == 0) {
                        const float* wp1 = &s_w[tap * 128 + ph * 32 + c8 * 8];
                        const float* wp2 = &s_w[1152 + tap * 128 + ph * 32 + c8 * 8];
#pragma unroll
                        for (int e = 0; e < 8; ++e) {
                            acc[0] = fmaf(zv[e], wp1[e], acc[0]);
                            acc[1] = fmaf(zv[e], wp2[e], acc[1]);
                        }
                    } else if (br == 1) {
#pragma unroll
                        for (int o = 0; o < 2; ++o) {
                            const float* wp = &s_w[(o * 9 + tap) * 128 + ph * 32 + c8 * 8];
#pragma unroll
                            for (int e = 0; e < 8; ++e)
                                acc[o] = fmaf(zv[e], wp[e], acc[o]);
                        }
                    } else {
#pragma unroll
                        for (int o = 0; o < 8; ++o) {
                            const float* wp = &s_w[(o * 9 + tap) * 128 + ph * 32 + c8 * 8];
#pragma unroll
                            for (int e = 0; e < 8; ++e)
                                acc[o] = fmaf(zv[e], wp[e], acc[o]);
                        }
                    }
                }
            }
    }
    const int pw = w0 + pcol_t, phh = h0 + prow_t;
    if (br == 0) {
        out[(size_t)n * 25600 + phh * 160 + pw] = acc[0] + bi_sh[0];
        out[102400 + (size_t)n * 25600 + phh * 160 + pw] = acc[1] + bi_ce[0];
    } else if (br == 1) {
#pragma unroll
        for (int o = 0; o < 2; ++o)
            out[204800 + ((size_t)(n * 2 + o)) * 25600 + phh * 160 + pw] = acc[o] + bi_p3[o];
    } else {
#pragma unroll
        for (int o = 0; o < 8; ++o)
            out[409600 + ((size_t)(n * 8 + o)) * 25600 + phh * 160 + pw] = acc[o] + bi_s3[o];
    }
}

// ---------------------------------------------------------------------------
// fallback heads (sequential path only)
template<int CO>
__global__ __launch_bounds__(256) void head_conv(const unsigned short* __restrict__ z,
                                                 const float* __restrict__ w,
                                                 const float* __restrict__ bias,
                                                 float* __restrict__ out) {
    __shared__ float s_w[CO * 9 * 128];
    for (int t = threadIdx.x; t < CO * 9 * 128; t += 256) {
        int ci = t % 128; int r = t / 128;
        int tap = r % 9;  int o = r / 9;
        s_w[t] = w[((size_t)(o * 128 + ci)) * 9 + tap];
    }
    __syncthreads();
    const int pos = blockIdx.x * 256 + threadIdx.x;
    const int pw = pos % 160, ph = (pos / 160) % 160, pn = pos / 25600;
    float acc[CO];
#pragma unroll
    for (int o = 0; o < CO; ++o) acc[o] = bias[o];
#pragma unroll
    for (int dh = 0; dh < 3; ++dh)
#pragma unroll
        for (int dw = 0; dw < 3; ++dw) {
            const int tap = dh * 3 + dw;
            const unsigned short* zp = z + ((size_t)((pn * 162 + ph + dh) * 162) + (pw + dw)) * 128;
            for (int c8 = 0; c8 < 16; ++c8) {
                uint4 v = *(const uint4*)(zp + c8 * 8);
                unsigned int ua[4] = {v.x, v.y, v.z, v.w};
                float xv[8];
#pragma unroll
                for (int j = 0; j < 4; ++j) {
                    xv[2 * j]     = bf2f((unsigned short)(ua[j] & 0xffffu));
                    xv[2 * j + 1] = bf2f((unsigned short)(ua[j] >> 16));
                }
#pragma unroll
                for (int o = 0; o < CO; ++o) {
                    const float* wp = &s_w[(o * 9 + tap) * 128 + c8 * 8];
#pragma unroll
                    for (int e = 0; e < 8; ++e) acc[o] = fmaf(xv[e], wp[e], acc[o]);
                }
            }
        }
#pragma unroll
    for (int o = 0; o < CO; ++o)
        out[((size_t)(pn * CO + o)) * 25600 + ph * 160 + pw] = acc[o];
}

__global__ __launch_bounds__(256) void head_conv_dual(const unsigned short* __restrict__ z,
                                                      const float* __restrict__ w1, const float* __restrict__ b1,
                                                      const float* __restrict__ w2, const float* __restrict__ b2,
                                                      float* __restrict__ out1, float* __restrict__ out2) {
    __shared__ float s_w[2 * 9 * 128];
    for (int t = threadIdx.x; t < 2 * 9 * 128; t += 256) {
        int ci = t % 128; int r = t / 128;
        int tap = r % 9;  int which = r / 9;
        const float* src = which ? w2 : w1;
        s_w[t] = src[(size_t)ci * 9 + tap];
    }
    __syncthreads();
    const int pos = blockIdx.x * 256 + threadIdx.x;
    const int pw = pos % 160, ph = (pos / 160) % 160, pn = pos / 25600;
    float a1 = b1[0], a2 = b2[0];
#pragma unroll
    for (int dh = 0; dh < 3; ++dh)
#pragma unroll
        for (int dw = 0; dw < 3; ++dw) {
            const int tap = dh * 3 + dw;
            const unsigned short* zp = z + ((size_t)((pn * 162 + ph + dh) * 162) + (pw + dw)) * 128;
            for (int c8 = 0; c8 < 16; ++c8) {
                uint4 v = *(const uint4*)(zp + c8 * 8);
                unsigned int ua[4] = {v.x, v.y, v.z, v.w};
                float xv[8];
#pragma unroll
                for (int j = 0; j < 4; ++j) {
                    xv[2 * j]     = bf2f((unsigned short)(ua[j] & 0xffffu));
                    xv[2 * j + 1] = bf2f((unsigned short)(ua[j] >> 16));
                }
                const float* wp1 = &s_w[tap * 128 + c8 * 8];
                const float* wp2 = &s_w[1152 + tap * 128 + c8 * 8];
#pragma unroll
                for (int e = 0; e < 8; ++e) {
                    a1 = fmaf(xv[e], wp1[e], a1);
                    a2 = fmaf(xv[e], wp2[e], a2);
                }
            }
        }
    out1[(size_t)pn * 25600 + ph * 160 + pw] = a1;
    out2[(size_t)pn * 25600 + ph * 160 + pw] = a2;
}

// ---------------------------------------------------------------------------
extern "C" void kernel_launch(void* const* d_in, const int* in_sizes, int n_in,
                              void* d_out, int out_size, void* d_ws, size_t ws_size,
                              hipStream_t stream) {
    const float* fpn = (const float*)d_in[0];
    const float* W1[3] = {(const float*)d_in[1],  (const float*)d_in[11], (const float*)d_in[19]};
    const float* G1[3] = {(const float*)d_in[2],  (const float*)d_in[12], (const float*)d_in[20]};
    const float* B1[3] = {(const float*)d_in[3],  (const float*)d_in[13], (const float*)d_in[21]};
    const float* W2[3] = {(const float*)d_in[4],  (const float*)d_in[14], (const float*)d_in[22]};
    const float* G2[3] = {(const float*)d_in[5],  (const float*)d_in[15], (const float*)d_in[23]};
    const float* B2[3] = {(const float*)d_in[6],  (const float*)d_in[16], (const float*)d_in[24]};
    const float* w_shrink = (const float*)d_in[7];  const float* b_shrink = (const float*)d_in[8];
    const float* w_cent   = (const float*)d_in[9];  const float* b_cent   = (const float*)d_in[10];
    const float* w_p3     = (const float*)d_in[17]; const float* b_p3     = (const float*)d_in[18];
    const float* w_s3     = (const float*)d_in[25]; const float* b_s3     = (const float*)d_in[26];
    float* out = (float*)d_out;

    const size_t S1 = (size_t)4 * 162 * 162 * 256;   // shorts per buf1
    const size_t S2 = (size_t)4 * 162 * 162 * 128;   // shorts per buf2
    const size_t need_fused = S1 * 2 * 4 + S2 * 2 * 3
                              + (size_t)9 * 294912 * 2 + 6 * 512 * 4;

    char* ws = (char*)d_ws;
    size_t off = 0;
    unsigned short* xpad = (unsigned short*)(ws + off); off += S1 * 2;
    const int NBR = (ws_size >= need_fused) ? 3 : 1;
    unsigned short* buf1 = (unsigned short*)(ws + off); off += S1 * 2 * NBR;
    unsigned short* buf2 = (unsigned short*)(ws + off); off += S2 * 2 * NBR;
    unsigned short* w1p  = (unsigned short*)(ws + off); off += (size_t)6 * 294912 * 2;
    unsigned short* w2p  = (unsigned short*)(ws + off); off += (size_t)3 * 294912 * 2;
    float* stats         = (float*)(ws + off);          off += (size_t)6 * 512 * 4;

    {
        int zcount = 82432 * (1 + NBR) + 41216 * NBR;
        int zb = (zcount + 255) / 256;
        prep<<<3 + zb + 12800 + 10368, 256, 0, stream>>>(
            fpn, xpad, buf1, S1, buf2, S2, NBR, zb, zcount, stats,
            W1[0], W1[1], W1[2], W2[0], W2[1], W2[2], w1p, w2p);
    }

    if (NBR == 3) {
        conv3x3_mfma<256, 800><<<2400, 256, 0, stream>>>(
            xpad, 0, w1p, (size_t)2 * 294912, buf1, S1, stats, 1024);
        bn_apply<256, 12800><<<38400, 256, 0, stream>>>(
            buf1, S1, stats, 1024, G1[0], G1[1], G1[2], B1[0], B1[1], B1[2]);
        conv3x3_mfma<128, 400><<<1200, 256, 0, stream>>>(
            buf1, S1, w2p, (size_t)294912, buf2, S2, stats + 512, 1024);
        heads_all<<<1200, 256, 0, stream>>>(
            buf2, S2, stats + 512, 1024,
            G2[0], G2[1], G2[2], B2[0], B2[1], B2[2],
            w_shrink, b_shrink, w_cent, b_cent, w_p3, b_p3, w_s3, b_s3, out);
    } else {
        for (int br = 0; br < 3; ++br) {
            conv3x3_mfma<256, 800><<<800, 256, 0, stream>>>(
                xpad, 0, w1p + (size_t)br * 2 * 294912, 0, buf1, 0, stats + br * 1024, 0);
            bn_apply<256, 12800><<<12800, 256, 0, stream>>>(
                buf1, 0, stats + br * 1024, 0, G1[br], G1[br], G1[br], B1[br], B1[br], B1[br]);
            conv3x3_mfma<128, 400><<<400, 256, 0, stream>>>(
                buf1, 0, w2p + (size_t)br * 294912, 0, buf2, 0, stats + 512 + br * 1024, 0);
            bn_apply<128, 6400><<<6400, 256, 0, stream>>>(
                buf2, 0, stats + 512 + br * 1024, 0, G2[br], G2[br], G2[br], B2[br], B2[br], B2[br]);
            if (br == 0) {
                head_conv_dual<<<400, 256, 0, stream>>>(buf2, w_shrink, b_shrink, w_cent, b_cent,
                                                        out, out + 102400);
            } else if (br == 1) {
                head_conv<2><<<400, 256, 0, stream>>>(buf2, w_p3, b_p3, out + 204800);
            } else {
                head_conv<8><<<400, 256, 0, stream>>>(buf2, w_s3, b_s3, out + 409600);
            }
        }
    }
}